// Round 10
// baseline (276.485 us; speedup 1.0000x reference)
//
#include <hip/hip_runtime.h>
#include <hip/hip_bf16.h>
#include <math.h>

#define Bn   4
#define Hh   56
#define Wn   56
#define Cn   256
#define NHn  8
#define HDn  32
#define Nn   3136
#define LLn  9
#define PLn  196
#define PWn  14
#define KTABn 2048
#define Mrows 12544
#define MP   224            // padded pool-key count (14 x 16)

// cvt5 segment offsets (elements)
#define XCNT   3211264
#define QWOFF  XCNT
#define KVWOFF (QWOFF + 65536)
#define SRWOFF (KVWOFF + 131072)
#define PWOFF  (SRWOFF + 65536)
#define TOTCVT (PWOFF + 65536)

typedef __attribute__((ext_vector_type(8))) short short8v;
typedef __attribute__((ext_vector_type(4))) float float4v;

__device__ __forceinline__ unsigned short f2b(float f) {
  __hip_bfloat16 h = __float2bfloat16(f);
  return *(unsigned short*)&h;
}
__device__ __forceinline__ float b2f(unsigned short u) {
  union { unsigned int i; float f; } x; x.i = ((unsigned int)u) << 16; return x.f;
}
__device__ __forceinline__ void u4_to8f(uint4 u, float* o) {
  o[0]=b2f((unsigned short)(u.x&0xffff)); o[1]=b2f((unsigned short)(u.x>>16));
  o[2]=b2f((unsigned short)(u.y&0xffff)); o[3]=b2f((unsigned short)(u.y>>16));
  o[4]=b2f((unsigned short)(u.z&0xffff)); o[5]=b2f((unsigned short)(u.z>>16));
  o[6]=b2f((unsigned short)(u.w&0xffff)); o[7]=b2f((unsigned short)(u.w>>16));
}

// ---------------------------------------------------------------------------
// Convert x + q_w + kv_w + sr_w + proj_w to one contiguous bf16 area.
// ---------------------------------------------------------------------------
__launch_bounds__(256)
__global__ void cvt5(const float* __restrict__ x, const float* __restrict__ qw,
                     const float* __restrict__ kvw, const float* __restrict__ srw,
                     const float* __restrict__ pw, unsigned short* __restrict__ dst)
{
  const int i = (blockIdx.x * 256 + threadIdx.x) * 4;
  const float* src; int off;
  if      (i < XCNT)   { src = x;   off = 0; }
  else if (i < KVWOFF) { src = qw;  off = QWOFF; }
  else if (i < SRWOFF) { src = kvw; off = KVWOFF; }
  else if (i < PWOFF)  { src = srw; off = SRWOFF; }
  else                 { src = pw;  off = PWOFF; }
  const float4 v = *(const float4*)(src + (i - off));
  ushort4 o2;
  o2.x = f2b(v.x); o2.y = f2b(v.y); o2.z = f2b(v.z); o2.w = f2b(v.w);
  *(ushort4*)(dst + i) = o2;
}

// ---------------------------------------------------------------------------
// bf16 MFMA GEMM.
// MODE 0 (proj): fp32 out via LDS-staged coalesced stores (two row-halves).
// MODE 1 (QKVS): bf16 out, fused norm epilogue, LDS-staged coalesced stores.
// Epilogues re-use the staging LDS after the K-loop's final barrier drains it:
// the scattered per-lane C-layout stores (64 x 2B/thread) were the round-9
// bottleneck (47us, all pipes idle).
// ---------------------------------------------------------------------------
template <int MODE>
__launch_bounds__(256)
__global__ void mgemm(const unsigned short* __restrict__ A,
                      const unsigned short* __restrict__ Wb,
                      const float* __restrict__ b0, const float* __restrict__ b1,
                      const float* __restrict__ b2, void* __restrict__ Cv, int Nc,
                      const float* __restrict__ sls, const float* __restrict__ qe,
                      const float* __restrict__ temp, float* __restrict__ Mq)
{
  __shared__ __align__(16) unsigned char smem[35072];
  unsigned short* As = (unsigned short*)smem;            // [128][64]
  unsigned short* Bs = (unsigned short*)(smem + 16384);  // [128][64]
  const int t = threadIdx.x;
  const int w = t >> 6, lane = t & 63;
  const int q = lane >> 4, ln = lane & 15;
  const int n0 = blockIdx.x * 128, m0 = blockIdx.y * 128;
  const int wm = (w >> 1) * 64, wn = (w & 1) * 64;

  float4v acc[4][4];
  #pragma unroll
  for (int mt = 0; mt < 4; ++mt)
    #pragma unroll
    for (int nt = 0; nt < 4; ++nt)
      acc[mt][nt] = (float4v){0.f, 0.f, 0.f, 0.f};

  for (int k0 = 0; k0 < 256; k0 += 64) {
    #pragma unroll
    for (int j = 0; j < 4; ++j) {
      const int u = t + 256 * j;
      const int r = u >> 3, cg = u & 7;
      const int cs = cg ^ (r & 7);
      const uint4 av = *(const uint4*)(A  + (size_t)(m0 + r) * 256 + k0 + cg * 8);
      *(uint4*)(As + r * 64 + cs * 8) = av;
      const uint4 bv = *(const uint4*)(Wb + (size_t)(n0 + r) * 256 + k0 + cg * 8);
      *(uint4*)(Bs + r * 64 + cs * 8) = bv;
    }
    __syncthreads();
    #pragma unroll
    for (int kk = 0; kk < 2; ++kk) {
      short8v af[4], bfr[4];
      const int cg = kk * 4 + q;
      #pragma unroll
      for (int mt = 0; mt < 4; ++mt) {
        const int r = wm + mt * 16 + ln;
        af[mt] = *(const short8v*)(As + r * 64 + (cg ^ (r & 7)) * 8);
      }
      #pragma unroll
      for (int nt = 0; nt < 4; ++nt) {
        const int r = wn + nt * 16 + ln;
        bfr[nt] = *(const short8v*)(Bs + r * 64 + (cg ^ (r & 7)) * 8);
      }
      #pragma unroll
      for (int mt = 0; mt < 4; ++mt)
        #pragma unroll
        for (int nt = 0; nt < 4; ++nt)
          acc[mt][nt] = __builtin_amdgcn_mfma_f32_16x16x32_bf16(af[mt], bfr[nt], acc[mt][nt], 0, 0, 0);
    }
    __syncthreads();
  }

  if constexpr (MODE == 0) {
    // fp32 out: two row-halves through LDS (64x132 fp32 = 33.8 KB each pass)
    float* C = (float*)Cv;
    float* tileF = (float*)smem;
    float bia[4];
    #pragma unroll
    for (int nt = 0; nt < 4; ++nt) bia[nt] = b0[n0 + wn + nt * 16 + ln];
    #pragma unroll
    for (int half = 0; half < 2; ++half) {
      if ((w >> 1) == half) {
        #pragma unroll
        for (int mt = 0; mt < 4; ++mt)
          #pragma unroll
          for (int r = 0; r < 4; ++r)
            #pragma unroll
            for (int nt = 0; nt < 4; ++nt)
              tileF[(mt*16 + q*4 + r) * 132 + wn + nt*16 + ln] = acc[mt][nt][r] + bia[nt];
      }
      __syncthreads();
      #pragma unroll
      for (int j = 0; j < 8; ++j) {
        const int i = j * 256 + t;            // 64 rows x 32 float4
        const int row = i >> 5, ch = i & 31;
        float4 v = *(const float4*)(tileF + row * 132 + ch * 4);
        *(float4*)(C + (size_t)(m0 + half * 64 + row) * Nc + n0 + ch * 4) = v;
      }
      __syncthreads();
    }
  } else {
    unsigned short* Cb = (unsigned short*)Cv;
    unsigned short* tileC = (unsigned short*)smem;     // [128][136] bf16
    const int seg = n0 >> 8;                 // block-uniform
    const int h0 = (n0 + wn) >> 5, h1 = h0 + 1;
    float spt0 = 0.f, spt1 = 0.f;
    if (seg == 0) { spt0 = log1pf(__expf(temp[h0])); spt1 = log1pf(__expf(temp[h1])); }
    float bia[4], qev[4];
    #pragma unroll
    for (int nt = 0; nt < 4; ++nt) {
      const int col = n0 + wn + nt * 16 + ln;
      bia[nt] = (seg == 0) ? b0[col] : (seg == 3 ? b2[col - 768] : b1[col - 256]);
      if (seg == 0) qev[nt] = qe[col];
    }
    #pragma unroll
    for (int mt = 0; mt < 4; ++mt) {
      #pragma unroll
      for (int r = 0; r < 4; ++r) {
        const int row = m0 + wm + mt * 16 + q * 4 + r;
        const int lrow = wm + mt * 16 + q * 4 + r;
        float vals[4];
        #pragma unroll
        for (int nt = 0; nt < 4; ++nt) vals[nt] = acc[mt][nt][r] + bia[nt];
        if (seg == 0) {
          float ss0 = vals[0]*vals[0] + vals[1]*vals[1];
          float ss1 = vals[2]*vals[2] + vals[3]*vals[3];
          #pragma unroll
          for (int mk = 1; mk <= 8; mk <<= 1) { ss0 += __shfl_xor(ss0, mk); ss1 += __shfl_xor(ss1, mk); }
          const float i0 = 1.f / fmaxf(sqrtf(ss0), 1e-12f);
          const float i1 = 1.f / fmaxf(sqrtf(ss1), 1e-12f);
          const int nidx = row % Nn, bb = row / Nn;
          const float sl = sls[nidx];
          float qsv[4];
          #pragma unroll
          for (int nt = 0; nt < 4; ++nt) {
            const float inv = (nt < 2) ? i0 : i1;
            const float sp  = (nt < 2) ? spt0 : spt1;
            qsv[nt] = (vals[nt] * inv + qev[nt]) * sp * sl;
          }
          float t0 = qsv[0]*qsv[0] + qsv[1]*qsv[1];
          float t1 = qsv[2]*qsv[2] + qsv[3]*qsv[3];
          #pragma unroll
          for (int mk = 1; mk <= 8; mk <<= 1) { t0 += __shfl_xor(t0, mk); t1 += __shfl_xor(t1, mk); }
          if (ln == 0) {
            Mq[((size_t)(bb * NHn + h0)) * Nn + nidx] = sqrtf(t0);
            Mq[((size_t)(bb * NHn + h1)) * Nn + nidx] = sqrtf(t1);
          }
          #pragma unroll
          for (int nt = 0; nt < 4; ++nt)
            tileC[lrow * 136 + wn + nt*16 + ln] = f2b(qsv[nt]);
        } else if (seg == 1) {
          float ss0 = vals[0]*vals[0] + vals[1]*vals[1];
          float ss1 = vals[2]*vals[2] + vals[3]*vals[3];
          #pragma unroll
          for (int mk = 1; mk <= 8; mk <<= 1) { ss0 += __shfl_xor(ss0, mk); ss1 += __shfl_xor(ss1, mk); }
          const float i0 = 1.f / fmaxf(sqrtf(ss0), 1e-12f);
          const float i1 = 1.f / fmaxf(sqrtf(ss1), 1e-12f);
          #pragma unroll
          for (int nt = 0; nt < 4; ++nt)
            tileC[lrow * 136 + wn + nt*16 + ln] = f2b(vals[nt] * ((nt < 2) ? i0 : i1));
        } else if (seg == 2) {
          #pragma unroll
          for (int nt = 0; nt < 4; ++nt)
            tileC[lrow * 136 + wn + nt*16 + ln] = f2b(vals[nt]);
        } else {
          #pragma unroll
          for (int nt = 0; nt < 4; ++nt) {
            const float v = vals[nt];
            tileC[lrow * 136 + wn + nt*16 + ln] =
              f2b(0.5f * v * (1.0f + erff(v * 0.70710678118654752f)));
          }
        }
      }
    }
    __syncthreads();
    // coalesced copy-out: 128 rows x 16 uint4
    #pragma unroll
    for (int j = 0; j < 8; ++j) {
      const int i = j * 256 + t;
      const int row = i >> 4, ch = i & 15;
      uint4 v = *(const uint4*)(tileC + row * 136 + ch * 8);
      *(uint4*)(Cb + (size_t)(m0 + row) * 1024 + n0 + ch * 8) = v;
    }
  }
}

// ---------------------------------------------------------------------------
// fp32 tiled GEMM (pool path only)
// ---------------------------------------------------------------------------
__launch_bounds__(256)
__global__ void gemm_k(const float* __restrict__ A, const float* __restrict__ W,
                       const float* __restrict__ bias, float* __restrict__ Co,
                       int Mr, int Nc, int K)
{
  __shared__ __align__(16) float As[16][64];
  __shared__ __align__(16) float Ws[16][64];
  const int t  = threadIdx.x;
  const int m0 = blockIdx.y * 64, n0 = blockIdx.x * 64;
  const int lm = t >> 2, lk = (t & 3) << 2;
  const int tx = t & 15, ty = t >> 4;
  float acc[4][4] = {};
  int arow = m0 + lm; if (arow >= Mr) arow = Mr - 1;
  const int wrow = n0 + lm;
  for (int k0 = 0; k0 < K; k0 += 16) {
    float4 av = *(const float4*)(A + (size_t)arow * K + k0 + lk);
    As[lk+0][lm] = av.x; As[lk+1][lm] = av.y; As[lk+2][lm] = av.z; As[lk+3][lm] = av.w;
    float4 wv = *(const float4*)(W + (size_t)wrow * K + k0 + lk);
    Ws[lk+0][lm] = wv.x; Ws[lk+1][lm] = wv.y; Ws[lk+2][lm] = wv.z; Ws[lk+3][lm] = wv.w;
    __syncthreads();
    #pragma unroll
    for (int k = 0; k < 16; ++k) {
      float4 a = *(const float4*)&As[k][ty << 2];
      float4 w = *(const float4*)&Ws[k][tx << 2];
      acc[0][0] += a.x*w.x; acc[0][1] += a.x*w.y; acc[0][2] += a.x*w.z; acc[0][3] += a.x*w.w;
      acc[1][0] += a.y*w.x; acc[1][1] += a.y*w.y; acc[1][2] += a.y*w.z; acc[1][3] += a.y*w.w;
      acc[2][0] += a.z*w.x; acc[2][1] += a.z*w.y; acc[2][2] += a.z*w.z; acc[2][3] += a.z*w.w;
      acc[3][0] += a.w*w.x; acc[3][1] += a.w*w.y; acc[3][2] += a.w*w.z; acc[3][3] += a.w*w.w;
    }
    __syncthreads();
  }
  #pragma unroll
  for (int i = 0; i < 4; ++i) {
    const int row = m0 + (ty << 2) + i;
    if (row >= Mr) continue;
    #pragma unroll
    for (int j = 0; j < 4; ++j) {
      const int col = n0 + (tx << 2) + j;
      Co[(size_t)row * Nc + col] = acc[i][j] + bias[col];
    }
  }
}

// ---------------------------------------------------------------------------
// 4x4 average pool of gelu'd sr (fused bf16 cols 768..1023) + LayerNorm over C
// ---------------------------------------------------------------------------
__launch_bounds__(256)
__global__ void pool_ln_k(const unsigned short* __restrict__ fused, float* __restrict__ pln,
                          const float* __restrict__ g, const float* __restrict__ bb)
{
  const int blk = blockIdx.x;
  const int b = blk / PLn, pc = blk % PLn;
  const int pi = pc / PWn, pj = pc % PWn;
  const int c = threadIdx.x;
  float s = 0.f;
  #pragma unroll
  for (int r = 0; r < 4; ++r)
    #pragma unroll
    for (int cc = 0; cc < 4; ++cc) {
      const int n = (pi*4 + r) * Wn + pj*4 + cc;
      s += b2f(fused[((size_t)b * Nn + n) * 1024 + 768 + c]);
    }
  s *= (1.f/16.f);
  float sum = s, sq = s*s;
  #pragma unroll
  for (int m = 32; m >= 1; m >>= 1) { sum += __shfl_xor(sum, m); sq += __shfl_xor(sq, m); }
  __shared__ float sm[8];
  const int lane = c & 63, wid = c >> 6;
  if (lane == 0) { sm[wid] = sum; sm[4+wid] = sq; }
  __syncthreads();
  const float tot  = sm[0]+sm[1]+sm[2]+sm[3];
  const float totq = sm[4]+sm[5]+sm[6]+sm[7];
  const float mu  = tot * (1.f/256.f);
  const float var = totq * (1.f/256.f) - mu*mu;
  pln[(size_t)blk * Cn + c] = (s - mu) / sqrtf(var + 1e-5f) * g[c] + bb[c];
}

// ---------------------------------------------------------------------------
// pool_pack: kvp -> kbf [bh][224 m][32 d] bf16 (L2-normed k, zero pad m>=196)
//            and vbf [bh][33 d][224 m] bf16 (v transposed; row 32 = ones)
// ---------------------------------------------------------------------------
__launch_bounds__(256)
__global__ void pool_pack(const float* __restrict__ kvp, unsigned short* __restrict__ kbf,
                          unsigned short* __restrict__ vbf)
{
  const int bh = blockIdx.x;
  const int b = bh >> 3, h = bh & 7;
  const int t = threadIdx.x, mg = t >> 5, d = t & 31;
  for (int mi = 0; mi < MP/8; ++mi) {
    const int m = mi * 8 + mg;
    float kv2 = 0.f, vv = 0.f;
    if (m < PLn) {
      kv2 = kvp[((size_t)(b * PLn + m)) * 512 + h * HDn + d];
      vv  = kvp[((size_t)(b * PLn + m)) * 512 + 256 + h * HDn + d];
    }
    float ssn = kv2 * kv2;
    #pragma unroll
    for (int mm = 16; mm >= 1; mm >>= 1) ssn += __shfl_xor(ssn, mm);
    const float kn = (m < PLn) ? kv2 / fmaxf(sqrtf(ssn), 1e-12f) : 0.f;
    kbf[((size_t)bh * MP + m) * HDn + d] = f2b(kn);
    vbf[((size_t)bh * 33 + d) * MP + m] = f2b(vv);
  }
  for (int i = t; i < MP; i += 256)
    vbf[((size_t)bh * 33 + 32) * MP + i] = f2b(1.0f);
}

// ---------------------------------------------------------------------------
// CPB MLP
// ---------------------------------------------------------------------------
__launch_bounds__(64)
__global__ void cpb_k(const float* __restrict__ rct, const float* __restrict__ w1,
                      const float* __restrict__ b1, const float* __restrict__ w2,
                      const float* __restrict__ b2, float* __restrict__ tab)
{
  const int r = blockIdx.x, t = threadIdx.x;
  const float c0 = rct[r*2], c1 = rct[r*2+1];
  float part[8] = {};
  #pragma unroll
  for (int jj = 0; jj < 8; ++jj) {
    const int j = t * 8 + jj;
    float hv = fmaxf(c0 * w1[j*2] + c1 * w1[j*2+1] + b1[j], 0.f);
    #pragma unroll
    for (int h = 0; h < 8; ++h) part[h] += hv * w2[h*512 + j];
  }
  #pragma unroll
  for (int h = 0; h < 8; ++h)
    for (int mm = 32; mm >= 1; mm >>= 1) part[h] += __shfl_xor(part[h], mm);
  if (t < 8) tab[r*8 + t] = part[t] + b2[t];
}

// ---------------------------------------------------------------------------
// global max over tab and rpb -> scal[0]
// ---------------------------------------------------------------------------
__launch_bounds__(256)
__global__ void redmax_k(const float* __restrict__ tab, const float* __restrict__ rpb,
                         float* __restrict__ scal)
{
  float mx = -1e30f;
  for (int i = threadIdx.x; i < KTABn*NHn; i += 256) mx = fmaxf(mx, tab[i]);
  if (threadIdx.x < NHn*LLn) mx = fmaxf(mx, rpb[threadIdx.x]);
  #pragma unroll
  for (int m = 32; m >= 1; m >>= 1) mx = fmaxf(mx, __shfl_xor(mx, m));
  __shared__ float sm[4];
  if ((threadIdx.x & 63) == 0) sm[threadIdx.x >> 6] = mx;
  __syncthreads();
  if (threadIdx.x == 0) scal[0] = fmaxf(fmaxf(sm[0], sm[1]), fmaxf(sm[2], sm[3]));
}

// ---------------------------------------------------------------------------
// bias_g2: bias2[h][n][224] bf16 = tab[rpi[n][m]][h] ; m>=196 -> -inf
// ---------------------------------------------------------------------------
__launch_bounds__(256)
__global__ void bias_g2(const int* __restrict__ rpi, const float* __restrict__ tab,
                        unsigned short* __restrict__ bias2)
{
  const int tid = blockIdx.x * 256 + threadIdx.x;
  const int n = tid / MP, m = tid - n * MP;
  if (m < PLn) {
    const int idx = rpi[(size_t)n * PLn + m];
    #pragma unroll
    for (int h = 0; h < NHn; ++h)
      bias2[((size_t)h * Nn + n) * MP + m] = f2b(tab[(size_t)idx * NHn + h]);
  } else {
    #pragma unroll
    for (int h = 0; h < NHn; ++h)
      bias2[((size_t)h * Nn + n) * MP + m] = 0xFF80;   // bf16 -inf
  }
}

// ---------------------------------------------------------------------------
// attn_pool: flash-style pool attention via MFMA; q read straight as bf16.
// ---------------------------------------------------------------------------
__launch_bounds__(256)
__global__ void attn_pool(const unsigned short* __restrict__ fused,
                          const unsigned short* __restrict__ kbf,
                          const unsigned short* __restrict__ vbf,
                          const unsigned short* __restrict__ bias2,
                          const float* __restrict__ Mq, const float* __restrict__ scal,
                          float* __restrict__ opart)
{
  __shared__ __align__(16) unsigned short sh[32256];
  unsigned short* k_lds = sh;
  unsigned short* v_lds = sh + 7168;
  unsigned short* p_lds = sh + 17920;
  const int t = threadIdx.x;
  const int w = t >> 6, lane = t & 63;
  const int ln = lane & 15, quad = lane >> 4;
  const int tile = blockIdx.x, h = blockIdx.y, b = blockIdx.z;
  const int bh = b * NHn + h;

  {
    const uint4* gk = (const uint4*)(kbf + (size_t)bh * (MP * HDn));
    uint4* lk = (uint4*)k_lds;
    for (int i = t; i < 896; i += 256) lk[i] = gk[i];
    const uint4* gv = (const uint4*)(vbf + (size_t)bh * (33 * MP));
    uint4* lv = (uint4*)v_lds;
    for (int i = t; i < 924; i += 256) lv[i] = gv[i];
  }
  __syncthreads();

  const int nb = tile * 64 + w * 16;
  const short8v afrag = *(const short8v*)(fused +
      ((size_t)(b * Nn + nb + ln)) * 1024 + h * HDn + quad * 8);
  float M4[4];
  const float sc = scal[0];
  #pragma unroll
  for (int r = 0; r < 4; ++r) M4[r] = Mq[(size_t)bh * Nn + nb + quad * 4 + r] + sc;

  unsigned short* pst = p_lds + w * (16 * MP);
  #pragma unroll
  for (int mt = 0; mt < 14; ++mt) {
    short8v bfrag = *(const short8v*)(k_lds + (mt * 16 + ln) * HDn + quad * 8);
    float4v s = __builtin_amdgcn_mfma_f32_16x16x32_bf16(afrag, bfrag,
                                                        (float4v){0.f,0.f,0.f,0.f}, 0, 0, 0);
    #pragma unroll
    for (int r = 0; r < 4; ++r) {
      const int nr = nb + quad * 4 + r;
      const float bv = b2f(bias2[((size_t)h * Nn + nr) * MP + mt * 16 + ln]);
      const float p = __expf(s[r] + bv - M4[r]);
      pst[(quad * 4 + r) * MP + mt * 16 + ln] = f2b(p);
    }
  }

  float4v accO[3];
  accO[0] = (float4v){0.f,0.f,0.f,0.f};
  accO[1] = (float4v){0.f,0.f,0.f,0.f};
  accO[2] = (float4v){0.f,0.f,0.f,0.f};
  #pragma unroll
  for (int kc = 0; kc < 7; ++kc) {
    short8v pa = *(const short8v*)(pst + ln * MP + kc * 32 + quad * 8);
    #pragma unroll
    for (int nt = 0; nt < 3; ++nt) {
      short8v vb = *(const short8v*)(v_lds + (nt * 16 + ln) * MP + kc * 32 + quad * 8);
      accO[nt] = __builtin_amdgcn_mfma_f32_16x16x32_bf16(pa, vb, accO[nt], 0, 0, 0);
    }
  }
  #pragma unroll
  for (int r = 0; r < 4; ++r) {
    const size_t base = ((size_t)bh * Nn + nb + quad * 4 + r) * 33;
    opart[base + ln]      = accO[0][r];
    opart[base + 16 + ln] = accO[1][r];
    if (ln == 0) opart[base + 32] = accO[2][r];
  }
}

// ---------------------------------------------------------------------------
// attn_loc: 9 local keys (bf16 fused) + cross-wave reduction + combine.
// ---------------------------------------------------------------------------
__launch_bounds__(256, 2)
__global__ void attn_loc(const unsigned short* __restrict__ fused,
                         const float* __restrict__ slsp, const float* __restrict__ temp,
                         const float* __restrict__ qe, const float* __restrict__ lt,
                         const float* __restrict__ lb, const float* __restrict__ rpb,
                         const float* __restrict__ scal, const float* __restrict__ Mq,
                         const float* __restrict__ opart, unsigned short* __restrict__ outp)
{
  __shared__ float red[4 * 64 * 33];
  __shared__ float lt_s[HDn * LLn];
  __shared__ float qe_s[HDn];
  __shared__ float lb_s[LLn], rpb_s[LLn];
  const int t = threadIdx.x;
  const int w = t >> 6, lane = t & 63;
  const int tile = blockIdx.x, h = blockIdx.y, b = blockIdx.z;
  const int n = tile * 64 + lane;
  const int bh = b * NHn + h;

  for (int i = t; i < HDn * LLn; i += 256) lt_s[i] = lt[h * HDn * LLn + i];
  if (t < HDn) qe_s[t] = qe[h * HDn + t];
  if (t < LLn) { lb_s[t] = lb[h * LLn + t]; rpb_s[t] = rpb[h * LLn + t]; }
  __syncthreads();

  const unsigned short* qp = fused + ((size_t)(b * Nn + n)) * 1024 + h * HDn;
  float qs[HDn];
  #pragma unroll
  for (int i = 0; i < 4; ++i) u4_to8f(((const uint4*)qp)[i], qs + i * 8);
  const float M = Mq[(size_t)bh * Nn + n] + scal[0];

  float acc[HDn], ext[HDn];
  #pragma unroll
  for (int d = 0; d < HDn; ++d) { acc[d] = 0.f; ext[d] = 0.f; }
  float l_run = 0.f;

  const float spt = log1pf(__expf(temp[h]));
  const float inv_qs = 1.f / (spt * slsp[n]);
  const int pi = n / Wn, pj = n % Wn;
  for (int lc = w; lc < LLn; lc += 4) {
    const int ii = pi + lc/3 - 1, jj = pj + (lc%3) - 1;
    if (ii < 0 || ii >= Hh || jj < 0 || jj >= Wn) continue;
    const int nb2 = ii * Wn + jj;
    float e = lb_s[lc];
    #pragma unroll
    for (int d = 0; d < HDn; ++d) e += (qs[d]*inv_qs - qe_s[d]) * lt_s[d*LLn + lc];
    const unsigned short* kr = fused + ((size_t)(b * Nn + nb2)) * 1024 + 256 + h * HDn;
    float kk[HDn];
    #pragma unroll
    for (int i = 0; i < 4; ++i) u4_to8f(((const uint4*)kr)[i], kk + i * 8);
    float p0=0,p1=0,p2=0,p3=0;
    #pragma unroll
    for (int dq = 0; dq < 8; ++dq) {
      const int d = dq*4;
      p0 += qs[d]*kk[d]; p1 += qs[d+1]*kk[d+1]; p2 += qs[d+2]*kk[d+2]; p3 += qs[d+3]*kk[d+3];
    }
    const float p = __expf(((p0+p1)+(p2+p3) + rpb_s[lc]) - M);
    l_run += p;
    float vv[HDn];
    #pragma unroll
    for (int i = 0; i < 4; ++i) u4_to8f(((const uint4*)(kr + 256))[i], vv + i * 8);
    #pragma unroll
    for (int d = 0; d < HDn; ++d) { acc[d] += p * vv[d]; ext[d] += e * vv[d]; }
  }

  float* myred = red + (w * 64 + lane) * 33;
  #pragma unroll
  for (int d = 0; d < HDn; ++d) myred[d] = acc[d];
  myred[32] = l_run;
  __syncthreads();
  const int n2 = t >> 2, dg = t & 3;
  float o[8], l_tot;
  {
    const float* r0 = red + n2 * 33, *r1 = r0 + 64*33, *r2 = r1 + 64*33, *r3 = r2 + 64*33;
    l_tot = r0[32] + r1[32] + r2[32] + r3[32];
    #pragma unroll
    for (int j = 0; j < 8; ++j)
      o[j] = r0[dg*8+j] + r1[dg*8+j] + r2[dg*8+j] + r3[dg*8+j];
  }
  __syncthreads();
  #pragma unroll
  for (int d = 0; d < HDn; ++d) myred[d] = ext[d];
  __syncthreads();
  float et[8];
  {
    const float* r0 = red + n2 * 33, *r1 = r0 + 64*33, *r2 = r1 + 64*33, *r3 = r2 + 64*33;
    #pragma unroll
    for (int j = 0; j < 8; ++j)
      et[j] = r0[dg*8+j] + r1[dg*8+j] + r2[dg*8+j] + r3[dg*8+j];
  }
  const size_t obase = ((size_t)bh * Nn + tile * 64 + n2) * 33;
  const float l_pool = opart[obase + 32];
  float op[8];
  #pragma unroll
  for (int j = 0; j < 8; ++j) op[j] = opart[obase + dg * 8 + j];
  const float invl = 1.f / (l_tot + l_pool);
  uint4 u;
  u.x = f2b((o[0]+op[0])*invl+et[0]) | ((unsigned int)f2b((o[1]+op[1])*invl+et[1]) << 16);
  u.y = f2b((o[2]+op[2])*invl+et[2]) | ((unsigned int)f2b((o[3]+op[3])*invl+et[3]) << 16);
  u.z = f2b((o[4]+op[4])*invl+et[4]) | ((unsigned int)f2b((o[5]+op[5])*invl+et[5]) << 16);
  u.w = f2b((o[6]+op[6])*invl+et[6]) | ((unsigned int)f2b((o[7]+op[7])*invl+et[7]) << 16);
  *(uint4*)(outp + ((size_t)b * Nn + tile*64 + n2) * Cn + h * HDn + dg * 8) = u;
}

// ---------------------------------------------------------------------------
extern "C" void kernel_launch(void* const* d_in, const int* in_sizes, int n_in,
                              void* d_out, int out_size, void* d_ws, size_t ws_size,
                              hipStream_t stream)
{
  const float* x    = (const float*)d_in[0];
  const int*   rpi  = (const int*)d_in[3];
  const float* rct  = (const float*)d_in[4];
  const float* sls  = (const float*)d_in[5];
  const float* q_w  = (const float*)d_in[7];
  const float* q_b  = (const float*)d_in[8];
  const float* kv_w = (const float*)d_in[9];
  const float* kv_b = (const float*)d_in[10];
  const float* sr_w = (const float*)d_in[11];
  const float* sr_b = (const float*)d_in[12];
  const float* ng   = (const float*)d_in[13];
  const float* nbta = (const float*)d_in[14];
  const float* c1w  = (const float*)d_in[15];
  const float* c1b  = (const float*)d_in[16];
  const float* c2w  = (const float*)d_in[17];
  const float* c2b  = (const float*)d_in[18];
  const float* temp = (const float*)d_in[19];
  const float* qe   = (const float*)d_in[20];
  const float* rpb  = (const float*)d_in[21];
  const float* lt   = (const float*)d_in[22];
  const float* lb   = (const float*)d_in[23];
  const float* pw   = (const float*)d_in[24];
  const float* pb   = (const float*)d_in[25];

  float* ws = (float*)d_ws;
  size_t o = 0;
  unsigned short* bf = (unsigned short*)(ws + o); o += TOTCVT / 2;
  unsigned short* fused = (unsigned short*)(ws + o); o += (size_t)Mrows * 512;  // bf16 [12544][1024]
  float* Mq    = ws + o;  o += (size_t)Bn * NHn * Nn;
  float* pln   = ws + o;  o += (size_t)Bn * PLn * Cn;
  float* kvp   = ws + o;  o += (size_t)Bn * PLn * 2 * Cn;
  unsigned short* kbf = (unsigned short*)(ws + o); o += (size_t)Bn * NHn * MP * HDn / 2;
  unsigned short* vbf = (unsigned short*)(ws + o); o += (size_t)Bn * NHn * 33 * MP / 2;
  float* tab   = ws + o;  o += (size_t)KTABn * NHn;
  float* scal  = ws + o;  o += 8;
  unsigned short* bias2 = (unsigned short*)(ws + o); o += (size_t)NHn * Nn * MP / 2;
  float* opart = ws + o;  o += (size_t)Bn * NHn * Nn * 33;
  unsigned short* outp  = (unsigned short*)(ws + o); o += (size_t)Mrows * Cn / 2;

  const unsigned short* xbf   = bf;
  const unsigned short* qkvsw = bf + QWOFF;
  const unsigned short* pwbf  = bf + PWOFF;

  cvt5<<<TOTCVT/1024, 256, 0, stream>>>(x, q_w, kv_w, sr_w, pw, bf);
  mgemm<1><<<dim3(8, 98), 256, 0, stream>>>(xbf, qkvsw, q_b, kv_b, sr_b, fused, 1024,
                                            sls, qe, temp, Mq);
  pool_ln_k<<<Bn*PLn, 256, 0, stream>>>(fused, pln, ng, nbta);
  gemm_k<<<dim3(8, 13), 256, 0, stream>>>(pln, kv_w, kv_b, kvp, Bn*PLn, 512, 256);
  pool_pack<<<Bn*NHn, 256, 0, stream>>>(kvp, kbf, vbf);
  cpb_k<<<KTABn, 64, 0, stream>>>(rct, c1w, c1b, c2w, c2b, tab);
  redmax_k<<<1, 256, 0, stream>>>(tab, rpb, scal);
  bias_g2<<<(Nn*MP)/256, 256, 0, stream>>>(rpi, tab, bias2);
  attn_pool<<<dim3(49, NHn, Bn), 256, 0, stream>>>(fused, kbf, vbf, bias2, Mq, scal, opart);
  attn_loc<<<dim3(49, NHn, Bn), 256, 0, stream>>>(fused, sls, temp, qe, lt, lb,
                                                  rpb, scal, Mq, opart, outp);
  mgemm<0><<<dim3(2, 98), 256, 0, stream>>>(outp, pwbf, pb, pb, pb, (float*)d_out, 256,
                                            nullptr, nullptr, nullptr, nullptr);
}

// Round 11
// 270.941 us; speedup vs baseline: 1.0205x; 1.0205x over previous
//
#include <hip/hip_runtime.h>
#include <hip/hip_bf16.h>
#include <math.h>

#define Bn   4
#define Hh   56
#define Wn   56
#define Cn   256
#define NHn  8
#define HDn  32
#define Nn   3136
#define LLn  9
#define PLn  196
#define PWn  14
#define KTABn 2048
#define Mrows 12544
#define MP   224            // padded pool-key count (14 x 16)

// cvt5 segment offsets (elements)
#define XCNT   3211264
#define QWOFF  XCNT
#define KVWOFF (QWOFF + 65536)
#define SRWOFF (KVWOFF + 131072)
#define PWOFF  (SRWOFF + 65536)
#define TOTCVT (PWOFF + 65536)

typedef __attribute__((ext_vector_type(8))) short short8v;
typedef __attribute__((ext_vector_type(4))) float float4v;

__device__ __forceinline__ unsigned short f2b(float f) {
  __hip_bfloat16 h = __float2bfloat16(f);
  return *(unsigned short*)&h;
}
__device__ __forceinline__ float b2f(unsigned short u) {
  union { unsigned int i; float f; } x; x.i = ((unsigned int)u) << 16; return x.f;
}
__device__ __forceinline__ void u4_to8f(uint4 u, float* o) {
  o[0]=b2f((unsigned short)(u.x&0xffff)); o[1]=b2f((unsigned short)(u.x>>16));
  o[2]=b2f((unsigned short)(u.y&0xffff)); o[3]=b2f((unsigned short)(u.y>>16));
  o[4]=b2f((unsigned short)(u.z&0xffff)); o[5]=b2f((unsigned short)(u.z>>16));
  o[6]=b2f((unsigned short)(u.w&0xffff)); o[7]=b2f((unsigned short)(u.w>>16));
}

// ---------------------------------------------------------------------------
// Convert x + q_w + kv_w + sr_w + proj_w to one contiguous bf16 area.
// ---------------------------------------------------------------------------
__launch_bounds__(256)
__global__ void cvt5(const float* __restrict__ x, const float* __restrict__ qw,
                     const float* __restrict__ kvw, const float* __restrict__ srw,
                     const float* __restrict__ pw, unsigned short* __restrict__ dst)
{
  const int i = (blockIdx.x * 256 + threadIdx.x) * 4;
  const float* src; int off;
  if      (i < XCNT)   { src = x;   off = 0; }
  else if (i < KVWOFF) { src = qw;  off = QWOFF; }
  else if (i < SRWOFF) { src = kvw; off = KVWOFF; }
  else if (i < PWOFF)  { src = srw; off = SRWOFF; }
  else                 { src = pw;  off = PWOFF; }
  const float4 v = *(const float4*)(src + (i - off));
  ushort4 o2;
  o2.x = f2b(v.x); o2.y = f2b(v.y); o2.z = f2b(v.z); o2.w = f2b(v.w);
  *(ushort4*)(dst + i) = o2;
}

// ---------------------------------------------------------------------------
// bf16 MFMA GEMM, 512 threads = 8 waves (all guaranteed co-resident: rounds
// 8-10 measured Occupancy ~13% with 4-wave blocks -> latency-bound; 8 waves
// per block doubles the minimum concurrent waves per CU).
// Tile 128x128; wave w: rows wm=(w>>1)*32 (+mt*16), cols wn=(w&1)*64 (+nt*16).
// MODE 0 (proj): fp32 out via LDS-staged stores (two row-halves).
// MODE 1 (QKVS): bf16 out, fused per-head norm epilogue, LDS-staged stores.
// ---------------------------------------------------------------------------
template <int MODE>
__launch_bounds__(512)
__global__ void mgemm(const unsigned short* __restrict__ A,
                      const unsigned short* __restrict__ Wb,
                      const float* __restrict__ b0, const float* __restrict__ b1,
                      const float* __restrict__ b2, void* __restrict__ Cv, int Nc,
                      const float* __restrict__ sls, const float* __restrict__ qe,
                      const float* __restrict__ temp, float* __restrict__ Mq)
{
  __shared__ __align__(16) unsigned char smem[34816];
  unsigned short* As = (unsigned short*)smem;            // [128][64]
  unsigned short* Bs = (unsigned short*)(smem + 16384);  // [128][64]
  const int t = threadIdx.x;
  const int w = t >> 6, lane = t & 63;
  const int q = lane >> 4, ln = lane & 15;
  const int n0 = blockIdx.x * 128, m0 = blockIdx.y * 128;
  const int wm = (w >> 1) * 32, wn = (w & 1) * 64;

  float4v acc[2][4];
  #pragma unroll
  for (int mt = 0; mt < 2; ++mt)
    #pragma unroll
    for (int nt = 0; nt < 4; ++nt)
      acc[mt][nt] = (float4v){0.f, 0.f, 0.f, 0.f};

  for (int k0 = 0; k0 < 256; k0 += 64) {
    #pragma unroll
    for (int j = 0; j < 2; ++j) {
      const int u = t + 512 * j;           // 0..1023
      const int r = u >> 3, cg = u & 7;
      const int cs = cg ^ (r & 7);
      const uint4 av = *(const uint4*)(A  + (size_t)(m0 + r) * 256 + k0 + cg * 8);
      *(uint4*)(As + r * 64 + cs * 8) = av;
      const uint4 bv = *(const uint4*)(Wb + (size_t)(n0 + r) * 256 + k0 + cg * 8);
      *(uint4*)(Bs + r * 64 + cs * 8) = bv;
    }
    __syncthreads();
    #pragma unroll
    for (int kk = 0; kk < 2; ++kk) {
      short8v af[2], bfr[4];
      const int cg = kk * 4 + q;
      #pragma unroll
      for (int mt = 0; mt < 2; ++mt) {
        const int r = wm + mt * 16 + ln;
        af[mt] = *(const short8v*)(As + r * 64 + (cg ^ (r & 7)) * 8);
      }
      #pragma unroll
      for (int nt = 0; nt < 4; ++nt) {
        const int r = wn + nt * 16 + ln;
        bfr[nt] = *(const short8v*)(Bs + r * 64 + (cg ^ (r & 7)) * 8);
      }
      #pragma unroll
      for (int mt = 0; mt < 2; ++mt)
        #pragma unroll
        for (int nt = 0; nt < 4; ++nt)
          acc[mt][nt] = __builtin_amdgcn_mfma_f32_16x16x32_bf16(af[mt], bfr[nt], acc[mt][nt], 0, 0, 0);
    }
    __syncthreads();
  }

  if constexpr (MODE == 0) {
    // fp32 out: two row-halves through LDS (64x132 fp32 = 33.8 KB each pass)
    float* C = (float*)Cv;
    float* tileF = (float*)smem;
    float bia[4];
    #pragma unroll
    for (int nt = 0; nt < 4; ++nt) bia[nt] = b0[n0 + wn + nt * 16 + ln];
    #pragma unroll
    for (int half = 0; half < 2; ++half) {
      if ((w >> 2) == half) {
        #pragma unroll
        for (int mt = 0; mt < 2; ++mt)
          #pragma unroll
          for (int r = 0; r < 4; ++r)
            #pragma unroll
            for (int nt = 0; nt < 4; ++nt)
              tileF[(wm - half*64 + mt*16 + q*4 + r) * 132 + wn + nt*16 + ln] = acc[mt][nt][r] + bia[nt];
      }
      __syncthreads();
      #pragma unroll
      for (int j = 0; j < 4; ++j) {
        const int i = j * 512 + t;            // 64 rows x 32 float4
        const int row = i >> 5, ch = i & 31;
        float4 v = *(const float4*)(tileF + row * 132 + ch * 4);
        *(float4*)(C + (size_t)(m0 + half * 64 + row) * Nc + n0 + ch * 4) = v;
      }
      __syncthreads();
    }
  } else {
    unsigned short* Cb = (unsigned short*)Cv;
    unsigned short* tileC = (unsigned short*)smem;     // [128][136] bf16
    const int seg = n0 >> 8;                 // block-uniform
    const int h0 = (n0 + wn) >> 5, h1 = h0 + 1;
    float spt0 = 0.f, spt1 = 0.f;
    if (seg == 0) { spt0 = log1pf(__expf(temp[h0])); spt1 = log1pf(__expf(temp[h1])); }
    float bia[4], qev[4];
    #pragma unroll
    for (int nt = 0; nt < 4; ++nt) {
      const int col = n0 + wn + nt * 16 + ln;
      bia[nt] = (seg == 0) ? b0[col] : (seg == 3 ? b2[col - 768] : b1[col - 256]);
      if (seg == 0) qev[nt] = qe[col];
    }
    #pragma unroll
    for (int mt = 0; mt < 2; ++mt) {
      #pragma unroll
      for (int r = 0; r < 4; ++r) {
        const int row = m0 + wm + mt * 16 + q * 4 + r;
        const int lrow = wm + mt * 16 + q * 4 + r;
        float vals[4];
        #pragma unroll
        for (int nt = 0; nt < 4; ++nt) vals[nt] = acc[mt][nt][r] + bia[nt];
        if (seg == 0) {
          float ss0 = vals[0]*vals[0] + vals[1]*vals[1];
          float ss1 = vals[2]*vals[2] + vals[3]*vals[3];
          #pragma unroll
          for (int mk = 1; mk <= 8; mk <<= 1) { ss0 += __shfl_xor(ss0, mk); ss1 += __shfl_xor(ss1, mk); }
          const float i0 = 1.f / fmaxf(sqrtf(ss0), 1e-12f);
          const float i1 = 1.f / fmaxf(sqrtf(ss1), 1e-12f);
          const int nidx = row % Nn, bb = row / Nn;
          const float sl = sls[nidx];
          float qsv[4];
          #pragma unroll
          for (int nt = 0; nt < 4; ++nt) {
            const float inv = (nt < 2) ? i0 : i1;
            const float sp  = (nt < 2) ? spt0 : spt1;
            qsv[nt] = (vals[nt] * inv + qev[nt]) * sp * sl;
          }
          float t0 = qsv[0]*qsv[0] + qsv[1]*qsv[1];
          float t1 = qsv[2]*qsv[2] + qsv[3]*qsv[3];
          #pragma unroll
          for (int mk = 1; mk <= 8; mk <<= 1) { t0 += __shfl_xor(t0, mk); t1 += __shfl_xor(t1, mk); }
          if (ln == 0) {
            Mq[((size_t)(bb * NHn + h0)) * Nn + nidx] = sqrtf(t0);
            Mq[((size_t)(bb * NHn + h1)) * Nn + nidx] = sqrtf(t1);
          }
          #pragma unroll
          for (int nt = 0; nt < 4; ++nt)
            tileC[lrow * 136 + wn + nt*16 + ln] = f2b(qsv[nt]);
        } else if (seg == 1) {
          float ss0 = vals[0]*vals[0] + vals[1]*vals[1];
          float ss1 = vals[2]*vals[2] + vals[3]*vals[3];
          #pragma unroll
          for (int mk = 1; mk <= 8; mk <<= 1) { ss0 += __shfl_xor(ss0, mk); ss1 += __shfl_xor(ss1, mk); }
          const float i0 = 1.f / fmaxf(sqrtf(ss0), 1e-12f);
          const float i1 = 1.f / fmaxf(sqrtf(ss1), 1e-12f);
          #pragma unroll
          for (int nt = 0; nt < 4; ++nt)
            tileC[lrow * 136 + wn + nt*16 + ln] = f2b(vals[nt] * ((nt < 2) ? i0 : i1));
        } else if (seg == 2) {
          #pragma unroll
          for (int nt = 0; nt < 4; ++nt)
            tileC[lrow * 136 + wn + nt*16 + ln] = f2b(vals[nt]);
        } else {
          #pragma unroll
          for (int nt = 0; nt < 4; ++nt) {
            const float v = vals[nt];
            tileC[lrow * 136 + wn + nt*16 + ln] =
              f2b(0.5f * v * (1.0f + erff(v * 0.70710678118654752f)));
          }
        }
      }
    }
    __syncthreads();
    // coalesced copy-out: 128 rows x 16 uint4 = 2048 / 512 thr
    #pragma unroll
    for (int j = 0; j < 4; ++j) {
      const int i = j * 512 + t;
      const int row = i >> 4, ch = i & 15;
      uint4 v = *(const uint4*)(tileC + row * 136 + ch * 8);
      *(uint4*)(Cb + (size_t)(m0 + row) * 1024 + n0 + ch * 8) = v;
    }
  }
}

// ---------------------------------------------------------------------------
// fp32 tiled GEMM (pool path only)
// ---------------------------------------------------------------------------
__launch_bounds__(256)
__global__ void gemm_k(const float* __restrict__ A, const float* __restrict__ W,
                       const float* __restrict__ bias, float* __restrict__ Co,
                       int Mr, int Nc, int K)
{
  __shared__ __align__(16) float As[16][64];
  __shared__ __align__(16) float Ws[16][64];
  const int t  = threadIdx.x;
  const int m0 = blockIdx.y * 64, n0 = blockIdx.x * 64;
  const int lm = t >> 2, lk = (t & 3) << 2;
  const int tx = t & 15, ty = t >> 4;
  float acc[4][4] = {};
  int arow = m0 + lm; if (arow >= Mr) arow = Mr - 1;
  const int wrow = n0 + lm;
  for (int k0 = 0; k0 < K; k0 += 16) {
    float4 av = *(const float4*)(A + (size_t)arow * K + k0 + lk);
    As[lk+0][lm] = av.x; As[lk+1][lm] = av.y; As[lk+2][lm] = av.z; As[lk+3][lm] = av.w;
    float4 wv = *(const float4*)(W + (size_t)wrow * K + k0 + lk);
    Ws[lk+0][lm] = wv.x; Ws[lk+1][lm] = wv.y; Ws[lk+2][lm] = wv.z; Ws[lk+3][lm] = wv.w;
    __syncthreads();
    #pragma unroll
    for (int k = 0; k < 16; ++k) {
      float4 a = *(const float4*)&As[k][ty << 2];
      float4 w = *(const float4*)&Ws[k][tx << 2];
      acc[0][0] += a.x*w.x; acc[0][1] += a.x*w.y; acc[0][2] += a.x*w.z; acc[0][3] += a.x*w.w;
      acc[1][0] += a.y*w.x; acc[1][1] += a.y*w.y; acc[1][2] += a.y*w.z; acc[1][3] += a.y*w.w;
      acc[2][0] += a.z*w.x; acc[2][1] += a.z*w.y; acc[2][2] += a.z*w.z; acc[2][3] += a.z*w.w;
      acc[3][0] += a.w*w.x; acc[3][1] += a.w*w.y; acc[3][2] += a.w*w.z; acc[3][3] += a.w*w.w;
    }
    __syncthreads();
  }
  #pragma unroll
  for (int i = 0; i < 4; ++i) {
    const int row = m0 + (ty << 2) + i;
    if (row >= Mr) continue;
    #pragma unroll
    for (int j = 0; j < 4; ++j) {
      const int col = n0 + (tx << 2) + j;
      Co[(size_t)row * Nc + col] = acc[i][j] + bias[col];
    }
  }
}

// ---------------------------------------------------------------------------
// 4x4 average pool of gelu'd sr (fused bf16 cols 768..1023) + LayerNorm over C
// ---------------------------------------------------------------------------
__launch_bounds__(256)
__global__ void pool_ln_k(const unsigned short* __restrict__ fused, float* __restrict__ pln,
                          const float* __restrict__ g, const float* __restrict__ bb)
{
  const int blk = blockIdx.x;
  const int b = blk / PLn, pc = blk % PLn;
  const int pi = pc / PWn, pj = pc % PWn;
  const int c = threadIdx.x;
  float s = 0.f;
  #pragma unroll
  for (int r = 0; r < 4; ++r)
    #pragma unroll
    for (int cc = 0; cc < 4; ++cc) {
      const int n = (pi*4 + r) * Wn + pj*4 + cc;
      s += b2f(fused[((size_t)b * Nn + n) * 1024 + 768 + c]);
    }
  s *= (1.f/16.f);
  float sum = s, sq = s*s;
  #pragma unroll
  for (int m = 32; m >= 1; m >>= 1) { sum += __shfl_xor(sum, m); sq += __shfl_xor(sq, m); }
  __shared__ float sm[8];
  const int lane = c & 63, wid = c >> 6;
  if (lane == 0) { sm[wid] = sum; sm[4+wid] = sq; }
  __syncthreads();
  const float tot  = sm[0]+sm[1]+sm[2]+sm[3];
  const float totq = sm[4]+sm[5]+sm[6]+sm[7];
  const float mu  = tot * (1.f/256.f);
  const float var = totq * (1.f/256.f) - mu*mu;
  pln[(size_t)blk * Cn + c] = (s - mu) / sqrtf(var + 1e-5f) * g[c] + bb[c];
}

// ---------------------------------------------------------------------------
// pool_pack: kvp -> kbf [bh][224 m][32 d] bf16 (L2-normed k, zero pad m>=196)
//            and vbf [bh][33 d][224 m] bf16 (v transposed; row 32 = ones)
// ---------------------------------------------------------------------------
__launch_bounds__(256)
__global__ void pool_pack(const float* __restrict__ kvp, unsigned short* __restrict__ kbf,
                          unsigned short* __restrict__ vbf)
{
  const int bh = blockIdx.x;
  const int b = bh >> 3, h = bh & 7;
  const int t = threadIdx.x, mg = t >> 5, d = t & 31;
  for (int mi = 0; mi < MP/8; ++mi) {
    const int m = mi * 8 + mg;
    float kv2 = 0.f, vv = 0.f;
    if (m < PLn) {
      kv2 = kvp[((size_t)(b * PLn + m)) * 512 + h * HDn + d];
      vv  = kvp[((size_t)(b * PLn + m)) * 512 + 256 + h * HDn + d];
    }
    float ssn = kv2 * kv2;
    #pragma unroll
    for (int mm = 16; mm >= 1; mm >>= 1) ssn += __shfl_xor(ssn, mm);
    const float kn = (m < PLn) ? kv2 / fmaxf(sqrtf(ssn), 1e-12f) : 0.f;
    kbf[((size_t)bh * MP + m) * HDn + d] = f2b(kn);
    vbf[((size_t)bh * 33 + d) * MP + m] = f2b(vv);
  }
  for (int i = t; i < MP; i += 256)
    vbf[((size_t)bh * 33 + 32) * MP + i] = f2b(1.0f);
}

// ---------------------------------------------------------------------------
// CPB MLP
// ---------------------------------------------------------------------------
__launch_bounds__(64)
__global__ void cpb_k(const float* __restrict__ rct, const float* __restrict__ w1,
                      const float* __restrict__ b1, const float* __restrict__ w2,
                      const float* __restrict__ b2, float* __restrict__ tab)
{
  const int r = blockIdx.x, t = threadIdx.x;
  const float c0 = rct[r*2], c1 = rct[r*2+1];
  float part[8] = {};
  #pragma unroll
  for (int jj = 0; jj < 8; ++jj) {
    const int j = t * 8 + jj;
    float hv = fmaxf(c0 * w1[j*2] + c1 * w1[j*2+1] + b1[j], 0.f);
    #pragma unroll
    for (int h = 0; h < 8; ++h) part[h] += hv * w2[h*512 + j];
  }
  #pragma unroll
  for (int h = 0; h < 8; ++h)
    for (int mm = 32; mm >= 1; mm >>= 1) part[h] += __shfl_xor(part[h], mm);
  if (t < 8) tab[r*8 + t] = part[t] + b2[t];
}

// ---------------------------------------------------------------------------
// global max over tab and rpb -> scal[0]
// ---------------------------------------------------------------------------
__launch_bounds__(256)
__global__ void redmax_k(const float* __restrict__ tab, const float* __restrict__ rpb,
                         float* __restrict__ scal)
{
  float mx = -1e30f;
  for (int i = threadIdx.x; i < KTABn*NHn; i += 256) mx = fmaxf(mx, tab[i]);
  if (threadIdx.x < NHn*LLn) mx = fmaxf(mx, rpb[threadIdx.x]);
  #pragma unroll
  for (int m = 32; m >= 1; m >>= 1) mx = fmaxf(mx, __shfl_xor(mx, m));
  __shared__ float sm[4];
  if ((threadIdx.x & 63) == 0) sm[threadIdx.x >> 6] = mx;
  __syncthreads();
  if (threadIdx.x == 0) scal[0] = fmaxf(fmaxf(sm[0], sm[1]), fmaxf(sm[2], sm[3]));
}

// ---------------------------------------------------------------------------
// bias_g2: bias2[h][n][224] bf16 = tab[rpi[n][m]][h] ; m>=196 -> -inf
// ---------------------------------------------------------------------------
__launch_bounds__(256)
__global__ void bias_g2(const int* __restrict__ rpi, const float* __restrict__ tab,
                        unsigned short* __restrict__ bias2)
{
  const int tid = blockIdx.x * 256 + threadIdx.x;
  const int n = tid / MP, m = tid - n * MP;
  if (m < PLn) {
    const int idx = rpi[(size_t)n * PLn + m];
    #pragma unroll
    for (int h = 0; h < NHn; ++h)
      bias2[((size_t)h * Nn + n) * MP + m] = f2b(tab[(size_t)idx * NHn + h]);
  } else {
    #pragma unroll
    for (int h = 0; h < NHn; ++h)
      bias2[((size_t)h * Nn + n) * MP + m] = 0xFF80;   // bf16 -inf
  }
}

// ---------------------------------------------------------------------------
// attn_pool: flash-style pool attention via MFMA; q read straight as bf16.
// ---------------------------------------------------------------------------
__launch_bounds__(256)
__global__ void attn_pool(const unsigned short* __restrict__ fused,
                          const unsigned short* __restrict__ kbf,
                          const unsigned short* __restrict__ vbf,
                          const unsigned short* __restrict__ bias2,
                          const float* __restrict__ Mq, const float* __restrict__ scal,
                          float* __restrict__ opart)
{
  __shared__ __align__(16) unsigned short sh[32256];
  unsigned short* k_lds = sh;
  unsigned short* v_lds = sh + 7168;
  unsigned short* p_lds = sh + 17920;
  const int t = threadIdx.x;
  const int w = t >> 6, lane = t & 63;
  const int ln = lane & 15, quad = lane >> 4;
  const int tile = blockIdx.x, h = blockIdx.y, b = blockIdx.z;
  const int bh = b * NHn + h;

  {
    const uint4* gk = (const uint4*)(kbf + (size_t)bh * (MP * HDn));
    uint4* lk = (uint4*)k_lds;
    for (int i = t; i < 896; i += 256) lk[i] = gk[i];
    const uint4* gv = (const uint4*)(vbf + (size_t)bh * (33 * MP));
    uint4* lv = (uint4*)v_lds;
    for (int i = t; i < 924; i += 256) lv[i] = gv[i];
  }
  __syncthreads();

  const int nb = tile * 64 + w * 16;
  const short8v afrag = *(const short8v*)(fused +
      ((size_t)(b * Nn + nb + ln)) * 1024 + h * HDn + quad * 8);
  float M4[4];
  const float sc = scal[0];
  #pragma unroll
  for (int r = 0; r < 4; ++r) M4[r] = Mq[(size_t)bh * Nn + nb + quad * 4 + r] + sc;

  unsigned short* pst = p_lds + w * (16 * MP);
  #pragma unroll
  for (int mt = 0; mt < 14; ++mt) {
    short8v bfrag = *(const short8v*)(k_lds + (mt * 16 + ln) * HDn + quad * 8);
    float4v s = __builtin_amdgcn_mfma_f32_16x16x32_bf16(afrag, bfrag,
                                                        (float4v){0.f,0.f,0.f,0.f}, 0, 0, 0);
    #pragma unroll
    for (int r = 0; r < 4; ++r) {
      const int nr = nb + quad * 4 + r;
      const float bv = b2f(bias2[((size_t)h * Nn + nr) * MP + mt * 16 + ln]);
      const float p = __expf(s[r] + bv - M4[r]);
      pst[(quad * 4 + r) * MP + mt * 16 + ln] = f2b(p);
    }
  }

  float4v accO[3];
  accO[0] = (float4v){0.f,0.f,0.f,0.f};
  accO[1] = (float4v){0.f,0.f,0.f,0.f};
  accO[2] = (float4v){0.f,0.f,0.f,0.f};
  #pragma unroll
  for (int kc = 0; kc < 7; ++kc) {
    short8v pa = *(const short8v*)(pst + ln * MP + kc * 32 + quad * 8);
    #pragma unroll
    for (int nt = 0; nt < 3; ++nt) {
      short8v vb = *(const short8v*)(v_lds + (nt * 16 + ln) * MP + kc * 32 + quad * 8);
      accO[nt] = __builtin_amdgcn_mfma_f32_16x16x32_bf16(pa, vb, accO[nt], 0, 0, 0);
    }
  }
  #pragma unroll
  for (int r = 0; r < 4; ++r) {
    const size_t base = ((size_t)bh * Nn + nb + quad * 4 + r) * 33;
    opart[base + ln]      = accO[0][r];
    opart[base + 16 + ln] = accO[1][r];
    if (ln == 0) opart[base + 32] = accO[2][r];
  }
}

// ---------------------------------------------------------------------------
// attn_loc: 9 local keys (bf16 fused) + cross-wave reduction + combine.
// ---------------------------------------------------------------------------
__launch_bounds__(256, 2)
__global__ void attn_loc(const unsigned short* __restrict__ fused,
                         const float* __restrict__ slsp, const float* __restrict__ temp,
                         const float* __restrict__ qe, const float* __restrict__ lt,
                         const float* __restrict__ lb, const float* __restrict__ rpb,
                         const float* __restrict__ scal, const float* __restrict__ Mq,
                         const float* __restrict__ opart, unsigned short* __restrict__ outp)
{
  __shared__ float red[4 * 64 * 33];
  __shared__ float lt_s[HDn * LLn];
  __shared__ float qe_s[HDn];
  __shared__ float lb_s[LLn], rpb_s[LLn];
  const int t = threadIdx.x;
  const int w = t >> 6, lane = t & 63;
  const int tile = blockIdx.x, h = blockIdx.y, b = blockIdx.z;
  const int n = tile * 64 + lane;
  const int bh = b * NHn + h;

  for (int i = t; i < HDn * LLn; i += 256) lt_s[i] = lt[h * HDn * LLn + i];
  if (t < HDn) qe_s[t] = qe[h * HDn + t];
  if (t < LLn) { lb_s[t] = lb[h * LLn + t]; rpb_s[t] = rpb[h * LLn + t]; }
  __syncthreads();

  const unsigned short* qp = fused + ((size_t)(b * Nn + n)) * 1024 + h * HDn;
  float qs[HDn];
  #pragma unroll
  for (int i = 0; i < 4; ++i) u4_to8f(((const uint4*)qp)[i], qs + i * 8);
  const float M = Mq[(size_t)bh * Nn + n] + scal[0];

  float acc[HDn], ext[HDn];
  #pragma unroll
  for (int d = 0; d < HDn; ++d) { acc[d] = 0.f; ext[d] = 0.f; }
  float l_run = 0.f;

  const float spt = log1pf(__expf(temp[h]));
  const float inv_qs = 1.f / (spt * slsp[n]);
  const int pi = n / Wn, pj = n % Wn;
  for (int lc = w; lc < LLn; lc += 4) {
    const int ii = pi + lc/3 - 1, jj = pj + (lc%3) - 1;
    if (ii < 0 || ii >= Hh || jj < 0 || jj >= Wn) continue;
    const int nb2 = ii * Wn + jj;
    float e = lb_s[lc];
    #pragma unroll
    for (int d = 0; d < HDn; ++d) e += (qs[d]*inv_qs - qe_s[d]) * lt_s[d*LLn + lc];
    const unsigned short* kr = fused + ((size_t)(b * Nn + nb2)) * 1024 + 256 + h * HDn;
    float kk[HDn];
    #pragma unroll
    for (int i = 0; i < 4; ++i) u4_to8f(((const uint4*)kr)[i], kk + i * 8);
    float p0=0,p1=0,p2=0,p3=0;
    #pragma unroll
    for (int dq = 0; dq < 8; ++dq) {
      const int d = dq*4;
      p0 += qs[d]*kk[d]; p1 += qs[d+1]*kk[d+1]; p2 += qs[d+2]*kk[d+2]; p3 += qs[d+3]*kk[d+3];
    }
    const float p = __expf(((p0+p1)+(p2+p3) + rpb_s[lc]) - M);
    l_run += p;
    float vv[HDn];
    #pragma unroll
    for (int i = 0; i < 4; ++i) u4_to8f(((const uint4*)(kr + 256))[i], vv + i * 8);
    #pragma unroll
    for (int d = 0; d < HDn; ++d) { acc[d] += p * vv[d]; ext[d] += e * vv[d]; }
  }

  float* myred = red + (w * 64 + lane) * 33;
  #pragma unroll
  for (int d = 0; d < HDn; ++d) myred[d] = acc[d];
  myred[32] = l_run;
  __syncthreads();
  const int n2 = t >> 2, dg = t & 3;
  float o[8], l_tot;
  {
    const float* r0 = red + n2 * 33, *r1 = r0 + 64*33, *r2 = r1 + 64*33, *r3 = r2 + 64*33;
    l_tot = r0[32] + r1[32] + r2[32] + r3[32];
    #pragma unroll
    for (int j = 0; j < 8; ++j)
      o[j] = r0[dg*8+j] + r1[dg*8+j] + r2[dg*8+j] + r3[dg*8+j];
  }
  __syncthreads();
  #pragma unroll
  for (int d = 0; d < HDn; ++d) myred[d] = ext[d];
  __syncthreads();
  float et[8];
  {
    const float* r0 = red + n2 * 33, *r1 = r0 + 64*33, *r2 = r1 + 64*33, *r3 = r2 + 64*33;
    #pragma unroll
    for (int j = 0; j < 8; ++j)
      et[j] = r0[dg*8+j] + r1[dg*8+j] + r2[dg*8+j] + r3[dg*8+j];
  }
  const size_t obase = ((size_t)bh * Nn + tile * 64 + n2) * 33;
  const float l_pool = opart[obase + 32];
  float op[8];
  #pragma unroll
  for (int j = 0; j < 8; ++j) op[j] = opart[obase + dg * 8 + j];
  const float invl = 1.f / (l_tot + l_pool);
  uint4 u;
  u.x = f2b((o[0]+op[0])*invl+et[0]) | ((unsigned int)f2b((o[1]+op[1])*invl+et[1]) << 16);
  u.y = f2b((o[2]+op[2])*invl+et[2]) | ((unsigned int)f2b((o[3]+op[3])*invl+et[3]) << 16);
  u.z = f2b((o[4]+op[4])*invl+et[4]) | ((unsigned int)f2b((o[5]+op[5])*invl+et[5]) << 16);
  u.w = f2b((o[6]+op[6])*invl+et[6]) | ((unsigned int)f2b((o[7]+op[7])*invl+et[7]) << 16);
  *(uint4*)(outp + ((size_t)b * Nn + tile*64 + n2) * Cn + h * HDn + dg * 8) = u;
}

// ---------------------------------------------------------------------------
extern "C" void kernel_launch(void* const* d_in, const int* in_sizes, int n_in,
                              void* d_out, int out_size, void* d_ws, size_t ws_size,
                              hipStream_t stream)
{
  const float* x    = (const float*)d_in[0];
  const int*   rpi  = (const int*)d_in[3];
  const float* rct  = (const float*)d_in[4];
  const float* sls  = (const float*)d_in[5];
  const float* q_w  = (const float*)d_in[7];
  const float* q_b  = (const float*)d_in[8];
  const float* kv_w = (const float*)d_in[9];
  const float* kv_b = (const float*)d_in[10];
  const float* sr_w = (const float*)d_in[11];
  const float* sr_b = (const float*)d_in[12];
  const float* ng   = (const float*)d_in[13];
  const float* nbta = (const float*)d_in[14];
  const float* c1w  = (const float*)d_in[15];
  const float* c1b  = (const float*)d_in[16];
  const float* c2w  = (const float*)d_in[17];
  const float* c2b  = (const float*)d_in[18];
  const float* temp = (const float*)d_in[19];
  const float* qe   = (const float*)d_in[20];
  const float* rpb  = (const float*)d_in[21];
  const float* lt   = (const float*)d_in[22];
  const float* lb   = (const float*)d_in[23];
  const float* pw   = (const float*)d_in[24];
  const float* pb   = (const float*)d_in[25];

  float* ws = (float*)d_ws;
  size_t o = 0;
  unsigned short* bf = (unsigned short*)(ws + o); o += TOTCVT / 2;
  unsigned short* fused = (unsigned short*)(ws + o); o += (size_t)Mrows * 512;  // bf16 [12544][1024]
  float* Mq    = ws + o;  o += (size_t)Bn * NHn * Nn;
  float* pln   = ws + o;  o += (size_t)Bn * PLn * Cn;
  float* kvp   = ws + o;  o += (size_t)Bn * PLn * 2 * Cn;
  unsigned short* kbf = (unsigned short*)(ws + o); o += (size_t)Bn * NHn * MP * HDn / 2;
  unsigned short* vbf = (unsigned short*)(ws + o); o += (size_t)Bn * NHn * 33 * MP / 2;
  float* tab   = ws + o;  o += (size_t)KTABn * NHn;
  float* scal  = ws + o;  o += 8;
  unsigned short* bias2 = (unsigned short*)(ws + o); o += (size_t)NHn * Nn * MP / 2;
  float* opart = ws + o;  o += (size_t)Bn * NHn * Nn * 33;
  unsigned short* outp  = (unsigned short*)(ws + o); o += (size_t)Mrows * Cn / 2;

  const unsigned short* xbf   = bf;
  const unsigned short* qkvsw = bf + QWOFF;
  const unsigned short* pwbf  = bf + PWOFF;

  cvt5<<<TOTCVT/1024, 256, 0, stream>>>(x, q_w, kv_w, sr_w, pw, bf);
  mgemm<1><<<dim3(8, 98), 512, 0, stream>>>(xbf, qkvsw, q_b, kv_b, sr_b, fused, 1024,
                                            sls, qe, temp, Mq);
  pool_ln_k<<<Bn*PLn, 256, 0, stream>>>(fused, pln, ng, nbta);
  gemm_k<<<dim3(8, 13), 256, 0, stream>>>(pln, kv_w, kv_b, kvp, Bn*PLn, 512, 256);
  pool_pack<<<Bn*NHn, 256, 0, stream>>>(kvp, kbf, vbf);
  cpb_k<<<KTABn, 64, 0, stream>>>(rct, c1w, c1b, c2w, c2b, tab);
  redmax_k<<<1, 256, 0, stream>>>(tab, rpb, scal);
  bias_g2<<<(Nn*MP)/256, 256, 0, stream>>>(rpi, tab, bias2);
  attn_pool<<<dim3(49, NHn, Bn), 256, 0, stream>>>(fused, kbf, vbf, bias2, Mq, scal, opart);
  attn_loc<<<dim3(49, NHn, Bn), 256, 0, stream>>>(fused, sls, temp, qe, lt, lb,
                                                  rpb, scal, Mq, opart, outp);
  mgemm<0><<<dim3(2, 98), 512, 0, stream>>>(outp, pwbf, pb, pb, pb, (float*)d_out, 256,
                                            nullptr, nullptr, nullptr, nullptr);
}

// Round 12
// 261.476 us; speedup vs baseline: 1.0574x; 1.0362x over previous
//
#include <hip/hip_runtime.h>
#include <hip/hip_bf16.h>
#include <math.h>

#define Bn   4
#define Hh   56
#define Wn   56
#define Cn   256
#define NHn  8
#define HDn  32
#define Nn   3136
#define LLn  9
#define PLn  196
#define PWn  14
#define KTABn 2048
#define Mrows 12544
#define MP   224            // padded pool-key count (14 x 16)

// cvt5 segment offsets (elements)
#define XCNT   3211264
#define QWOFF  XCNT
#define KVWOFF (QWOFF + 65536)
#define SRWOFF (KVWOFF + 131072)
#define PWOFF  (SRWOFF + 65536)
#define TOTCVT (PWOFF + 65536)

typedef __attribute__((ext_vector_type(8))) short short8v;
typedef __attribute__((ext_vector_type(4))) float float4v;

__device__ __forceinline__ unsigned short f2b(float f) {
  __hip_bfloat16 h = __float2bfloat16(f);
  return *(unsigned short*)&h;
}
__device__ __forceinline__ float b2f(unsigned short u) {
  union { unsigned int i; float f; } x; x.i = ((unsigned int)u) << 16; return x.f;
}
__device__ __forceinline__ void u4_to8f(uint4 u, float* o) {
  o[0]=b2f((unsigned short)(u.x&0xffff)); o[1]=b2f((unsigned short)(u.x>>16));
  o[2]=b2f((unsigned short)(u.y&0xffff)); o[3]=b2f((unsigned short)(u.y>>16));
  o[4]=b2f((unsigned short)(u.z&0xffff)); o[5]=b2f((unsigned short)(u.z>>16));
  o[6]=b2f((unsigned short)(u.w&0xffff)); o[7]=b2f((unsigned short)(u.w>>16));
}

// ---------------------------------------------------------------------------
// Convert x + q_w + kv_w + sr_w + proj_w to one contiguous bf16 area.
// ---------------------------------------------------------------------------
__launch_bounds__(256)
__global__ void cvt5(const float* __restrict__ x, const float* __restrict__ qw,
                     const float* __restrict__ kvw, const float* __restrict__ srw,
                     const float* __restrict__ pw, unsigned short* __restrict__ dst)
{
  const int i = (blockIdx.x * 256 + threadIdx.x) * 4;
  const float* src; int off;
  if      (i < XCNT)   { src = x;   off = 0; }
  else if (i < KVWOFF) { src = qw;  off = QWOFF; }
  else if (i < SRWOFF) { src = kvw; off = KVWOFF; }
  else if (i < PWOFF)  { src = srw; off = SRWOFF; }
  else                 { src = pw;  off = PWOFF; }
  const float4 v = *(const float4*)(src + (i - off));
  ushort4 o2;
  o2.x = f2b(v.x); o2.y = f2b(v.y); o2.z = f2b(v.z); o2.w = f2b(v.w);
  *(ushort4*)(dst + i) = o2;
}

// ---------------------------------------------------------------------------
// bf16 MFMA GEMM, 512 threads = 8 waves.
// MODE 0 (proj): fp32 out via LDS-staged stores (two row-halves).
// MODE 1 (QKVS): bf16 out, fused per-head norm epilogue, LDS-staged stores.
// ---------------------------------------------------------------------------
template <int MODE>
__launch_bounds__(512)
__global__ void mgemm(const unsigned short* __restrict__ A,
                      const unsigned short* __restrict__ Wb,
                      const float* __restrict__ b0, const float* __restrict__ b1,
                      const float* __restrict__ b2, void* __restrict__ Cv, int Nc,
                      const float* __restrict__ sls, const float* __restrict__ qe,
                      const float* __restrict__ temp, float* __restrict__ Mq)
{
  __shared__ __align__(16) unsigned char smem[34816];
  unsigned short* As = (unsigned short*)smem;            // [128][64]
  unsigned short* Bs = (unsigned short*)(smem + 16384);  // [128][64]
  const int t = threadIdx.x;
  const int w = t >> 6, lane = t & 63;
  const int q = lane >> 4, ln = lane & 15;
  const int n0 = blockIdx.x * 128, m0 = blockIdx.y * 128;
  const int wm = (w >> 1) * 32, wn = (w & 1) * 64;

  float4v acc[2][4];
  #pragma unroll
  for (int mt = 0; mt < 2; ++mt)
    #pragma unroll
    for (int nt = 0; nt < 4; ++nt)
      acc[mt][nt] = (float4v){0.f, 0.f, 0.f, 0.f};

  for (int k0 = 0; k0 < 256; k0 += 64) {
    #pragma unroll
    for (int j = 0; j < 2; ++j) {
      const int u = t + 512 * j;
      const int r = u >> 3, cg = u & 7;
      const int cs = cg ^ (r & 7);
      const uint4 av = *(const uint4*)(A  + (size_t)(m0 + r) * 256 + k0 + cg * 8);
      *(uint4*)(As + r * 64 + cs * 8) = av;
      const uint4 bv = *(const uint4*)(Wb + (size_t)(n0 + r) * 256 + k0 + cg * 8);
      *(uint4*)(Bs + r * 64 + cs * 8) = bv;
    }
    __syncthreads();
    #pragma unroll
    for (int kk = 0; kk < 2; ++kk) {
      short8v af[2], bfr[4];
      const int cg = kk * 4 + q;
      #pragma unroll
      for (int mt = 0; mt < 2; ++mt) {
        const int r = wm + mt * 16 + ln;
        af[mt] = *(const short8v*)(As + r * 64 + (cg ^ (r & 7)) * 8);
      }
      #pragma unroll
      for (int nt = 0; nt < 4; ++nt) {
        const int r = wn + nt * 16 + ln;
        bfr[nt] = *(const short8v*)(Bs + r * 64 + (cg ^ (r & 7)) * 8);
      }
      #pragma unroll
      for (int mt = 0; mt < 2; ++mt)
        #pragma unroll
        for (int nt = 0; nt < 4; ++nt)
          acc[mt][nt] = __builtin_amdgcn_mfma_f32_16x16x32_bf16(af[mt], bfr[nt], acc[mt][nt], 0, 0, 0);
    }
    __syncthreads();
  }

  if constexpr (MODE == 0) {
    float* C = (float*)Cv;
    float* tileF = (float*)smem;
    float bia[4];
    #pragma unroll
    for (int nt = 0; nt < 4; ++nt) bia[nt] = b0[n0 + wn + nt * 16 + ln];
    #pragma unroll
    for (int half = 0; half < 2; ++half) {
      if ((w >> 2) == half) {
        #pragma unroll
        for (int mt = 0; mt < 2; ++mt)
          #pragma unroll
          for (int r = 0; r < 4; ++r)
            #pragma unroll
            for (int nt = 0; nt < 4; ++nt)
              tileF[(wm - half*64 + mt*16 + q*4 + r) * 132 + wn + nt*16 + ln] = acc[mt][nt][r] + bia[nt];
      }
      __syncthreads();
      #pragma unroll
      for (int j = 0; j < 4; ++j) {
        const int i = j * 512 + t;
        const int row = i >> 5, ch = i & 31;
        float4 v = *(const float4*)(tileF + row * 132 + ch * 4);
        *(float4*)(C + (size_t)(m0 + half * 64 + row) * Nc + n0 + ch * 4) = v;
      }
      __syncthreads();
    }
  } else {
    unsigned short* Cb = (unsigned short*)Cv;
    unsigned short* tileC = (unsigned short*)smem;     // [128][136] bf16
    const int seg = n0 >> 8;
    const int h0 = (n0 + wn) >> 5, h1 = h0 + 1;
    float spt0 = 0.f, spt1 = 0.f;
    if (seg == 0) { spt0 = log1pf(__expf(temp[h0])); spt1 = log1pf(__expf(temp[h1])); }
    float bia[4], qev[4];
    #pragma unroll
    for (int nt = 0; nt < 4; ++nt) {
      const int col = n0 + wn + nt * 16 + ln;
      bia[nt] = (seg == 0) ? b0[col] : (seg == 3 ? b2[col - 768] : b1[col - 256]);
      if (seg == 0) qev[nt] = qe[col];
    }
    #pragma unroll
    for (int mt = 0; mt < 2; ++mt) {
      #pragma unroll
      for (int r = 0; r < 4; ++r) {
        const int row = m0 + wm + mt * 16 + q * 4 + r;
        const int lrow = wm + mt * 16 + q * 4 + r;
        float vals[4];
        #pragma unroll
        for (int nt = 0; nt < 4; ++nt) vals[nt] = acc[mt][nt][r] + bia[nt];
        if (seg == 0) {
          float ss0 = vals[0]*vals[0] + vals[1]*vals[1];
          float ss1 = vals[2]*vals[2] + vals[3]*vals[3];
          #pragma unroll
          for (int mk = 1; mk <= 8; mk <<= 1) { ss0 += __shfl_xor(ss0, mk); ss1 += __shfl_xor(ss1, mk); }
          const float i0 = 1.f / fmaxf(sqrtf(ss0), 1e-12f);
          const float i1 = 1.f / fmaxf(sqrtf(ss1), 1e-12f);
          const int nidx = row % Nn, bb = row / Nn;
          const float sl = sls[nidx];
          float qsv[4];
          #pragma unroll
          for (int nt = 0; nt < 4; ++nt) {
            const float inv = (nt < 2) ? i0 : i1;
            const float sp  = (nt < 2) ? spt0 : spt1;
            qsv[nt] = (vals[nt] * inv + qev[nt]) * sp * sl;
          }
          float t0 = qsv[0]*qsv[0] + qsv[1]*qsv[1];
          float t1 = qsv[2]*qsv[2] + qsv[3]*qsv[3];
          #pragma unroll
          for (int mk = 1; mk <= 8; mk <<= 1) { t0 += __shfl_xor(t0, mk); t1 += __shfl_xor(t1, mk); }
          if (ln == 0) {
            Mq[((size_t)(bb * NHn + h0)) * Nn + nidx] = sqrtf(t0);
            Mq[((size_t)(bb * NHn + h1)) * Nn + nidx] = sqrtf(t1);
          }
          #pragma unroll
          for (int nt = 0; nt < 4; ++nt)
            tileC[lrow * 136 + wn + nt*16 + ln] = f2b(qsv[nt]);
        } else if (seg == 1) {
          float ss0 = vals[0]*vals[0] + vals[1]*vals[1];
          float ss1 = vals[2]*vals[2] + vals[3]*vals[3];
          #pragma unroll
          for (int mk = 1; mk <= 8; mk <<= 1) { ss0 += __shfl_xor(ss0, mk); ss1 += __shfl_xor(ss1, mk); }
          const float i0 = 1.f / fmaxf(sqrtf(ss0), 1e-12f);
          const float i1 = 1.f / fmaxf(sqrtf(ss1), 1e-12f);
          #pragma unroll
          for (int nt = 0; nt < 4; ++nt)
            tileC[lrow * 136 + wn + nt*16 + ln] = f2b(vals[nt] * ((nt < 2) ? i0 : i1));
        } else if (seg == 2) {
          #pragma unroll
          for (int nt = 0; nt < 4; ++nt)
            tileC[lrow * 136 + wn + nt*16 + ln] = f2b(vals[nt]);
        } else {
          #pragma unroll
          for (int nt = 0; nt < 4; ++nt) {
            const float v = vals[nt];
            tileC[lrow * 136 + wn + nt*16 + ln] =
              f2b(0.5f * v * (1.0f + erff(v * 0.70710678118654752f)));
          }
        }
      }
    }
    __syncthreads();
    #pragma unroll
    for (int j = 0; j < 4; ++j) {
      const int i = j * 512 + t;
      const int row = i >> 4, ch = i & 15;
      uint4 v = *(const uint4*)(tileC + row * 136 + ch * 8);
      *(uint4*)(Cb + (size_t)(m0 + row) * 1024 + n0 + ch * 8) = v;
    }
  }
}

// ---------------------------------------------------------------------------
// fp32 tiled GEMM (pool path only)
// ---------------------------------------------------------------------------
__launch_bounds__(256)
__global__ void gemm_k(const float* __restrict__ A, const float* __restrict__ W,
                       const float* __restrict__ bias, float* __restrict__ Co,
                       int Mr, int Nc, int K)
{
  __shared__ __align__(16) float As[16][64];
  __shared__ __align__(16) float Ws[16][64];
  const int t  = threadIdx.x;
  const int m0 = blockIdx.y * 64, n0 = blockIdx.x * 64;
  const int lm = t >> 2, lk = (t & 3) << 2;
  const int tx = t & 15, ty = t >> 4;
  float acc[4][4] = {};
  int arow = m0 + lm; if (arow >= Mr) arow = Mr - 1;
  const int wrow = n0 + lm;
  for (int k0 = 0; k0 < K; k0 += 16) {
    float4 av = *(const float4*)(A + (size_t)arow * K + k0 + lk);
    As[lk+0][lm] = av.x; As[lk+1][lm] = av.y; As[lk+2][lm] = av.z; As[lk+3][lm] = av.w;
    float4 wv = *(const float4*)(W + (size_t)wrow * K + k0 + lk);
    Ws[lk+0][lm] = wv.x; Ws[lk+1][lm] = wv.y; Ws[lk+2][lm] = wv.z; Ws[lk+3][lm] = wv.w;
    __syncthreads();
    #pragma unroll
    for (int k = 0; k < 16; ++k) {
      float4 a = *(const float4*)&As[k][ty << 2];
      float4 w = *(const float4*)&Ws[k][tx << 2];
      acc[0][0] += a.x*w.x; acc[0][1] += a.x*w.y; acc[0][2] += a.x*w.z; acc[0][3] += a.x*w.w;
      acc[1][0] += a.y*w.x; acc[1][1] += a.y*w.y; acc[1][2] += a.y*w.z; acc[1][3] += a.y*w.w;
      acc[2][0] += a.z*w.x; acc[2][1] += a.z*w.y; acc[2][2] += a.z*w.z; acc[2][3] += a.z*w.w;
      acc[3][0] += a.w*w.x; acc[3][1] += a.w*w.y; acc[3][2] += a.w*w.z; acc[3][3] += a.w*w.w;
    }
    __syncthreads();
  }
  #pragma unroll
  for (int i = 0; i < 4; ++i) {
    const int row = m0 + (ty << 2) + i;
    if (row >= Mr) continue;
    #pragma unroll
    for (int j = 0; j < 4; ++j) {
      const int col = n0 + (tx << 2) + j;
      Co[(size_t)row * Nc + col] = acc[i][j] + bias[col];
    }
  }
}

// ---------------------------------------------------------------------------
// 4x4 average pool of gelu'd sr (fused bf16 cols 768..1023) + LayerNorm over C
// ---------------------------------------------------------------------------
__launch_bounds__(256)
__global__ void pool_ln_k(const unsigned short* __restrict__ fused, float* __restrict__ pln,
                          const float* __restrict__ g, const float* __restrict__ bb)
{
  const int blk = blockIdx.x;
  const int b = blk / PLn, pc = blk % PLn;
  const int pi = pc / PWn, pj = pc % PWn;
  const int c = threadIdx.x;
  float s = 0.f;
  #pragma unroll
  for (int r = 0; r < 4; ++r)
    #pragma unroll
    for (int cc = 0; cc < 4; ++cc) {
      const int n = (pi*4 + r) * Wn + pj*4 + cc;
      s += b2f(fused[((size_t)b * Nn + n) * 1024 + 768 + c]);
    }
  s *= (1.f/16.f);
  float sum = s, sq = s*s;
  #pragma unroll
  for (int m = 32; m >= 1; m >>= 1) { sum += __shfl_xor(sum, m); sq += __shfl_xor(sq, m); }
  __shared__ float sm[8];
  const int lane = c & 63, wid = c >> 6;
  if (lane == 0) { sm[wid] = sum; sm[4+wid] = sq; }
  __syncthreads();
  const float tot  = sm[0]+sm[1]+sm[2]+sm[3];
  const float totq = sm[4]+sm[5]+sm[6]+sm[7];
  const float mu  = tot * (1.f/256.f);
  const float var = totq * (1.f/256.f) - mu*mu;
  pln[(size_t)blk * Cn + c] = (s - mu) / sqrtf(var + 1e-5f) * g[c] + bb[c];
}

// ---------------------------------------------------------------------------
// pool_pack: kvp -> kbf [bh][224 m][32 d] bf16 (L2-normed k, zero pad m>=196)
//            and vbf [bh][33 d][224 m] bf16 (v transposed; row 32 = ones)
// ---------------------------------------------------------------------------
__launch_bounds__(256)
__global__ void pool_pack(const float* __restrict__ kvp, unsigned short* __restrict__ kbf,
                          unsigned short* __restrict__ vbf)
{
  const int bh = blockIdx.x;
  const int b = bh >> 3, h = bh & 7;
  const int t = threadIdx.x, mg = t >> 5, d = t & 31;
  for (int mi = 0; mi < MP/8; ++mi) {
    const int m = mi * 8 + mg;
    float kv2 = 0.f, vv = 0.f;
    if (m < PLn) {
      kv2 = kvp[((size_t)(b * PLn + m)) * 512 + h * HDn + d];
      vv  = kvp[((size_t)(b * PLn + m)) * 512 + 256 + h * HDn + d];
    }
    float ssn = kv2 * kv2;
    #pragma unroll
    for (int mm = 16; mm >= 1; mm >>= 1) ssn += __shfl_xor(ssn, mm);
    const float kn = (m < PLn) ? kv2 / fmaxf(sqrtf(ssn), 1e-12f) : 0.f;
    kbf[((size_t)bh * MP + m) * HDn + d] = f2b(kn);
    vbf[((size_t)bh * 33 + d) * MP + m] = f2b(vv);
  }
  for (int i = t; i < MP; i += 256)
    vbf[((size_t)bh * 33 + 32) * MP + i] = f2b(1.0f);
}

// ---------------------------------------------------------------------------
// CPB MLP
// ---------------------------------------------------------------------------
__launch_bounds__(64)
__global__ void cpb_k(const float* __restrict__ rct, const float* __restrict__ w1,
                      const float* __restrict__ b1, const float* __restrict__ w2,
                      const float* __restrict__ b2, float* __restrict__ tab)
{
  const int r = blockIdx.x, t = threadIdx.x;
  const float c0 = rct[r*2], c1 = rct[r*2+1];
  float part[8] = {};
  #pragma unroll
  for (int jj = 0; jj < 8; ++jj) {
    const int j = t * 8 + jj;
    float hv = fmaxf(c0 * w1[j*2] + c1 * w1[j*2+1] + b1[j], 0.f);
    #pragma unroll
    for (int h = 0; h < 8; ++h) part[h] += hv * w2[h*512 + j];
  }
  #pragma unroll
  for (int h = 0; h < 8; ++h)
    for (int mm = 32; mm >= 1; mm >>= 1) part[h] += __shfl_xor(part[h], mm);
  if (t < 8) tab[r*8 + t] = part[t] + b2[t];
}

// ---------------------------------------------------------------------------
// global max over tab and rpb -> scal[0]
// ---------------------------------------------------------------------------
__launch_bounds__(256)
__global__ void redmax_k(const float* __restrict__ tab, const float* __restrict__ rpb,
                         float* __restrict__ scal)
{
  float mx = -1e30f;
  for (int i = threadIdx.x; i < KTABn*NHn; i += 256) mx = fmaxf(mx, tab[i]);
  if (threadIdx.x < NHn*LLn) mx = fmaxf(mx, rpb[threadIdx.x]);
  #pragma unroll
  for (int m = 32; m >= 1; m >>= 1) mx = fmaxf(mx, __shfl_xor(mx, m));
  __shared__ float sm[4];
  if ((threadIdx.x & 63) == 0) sm[threadIdx.x >> 6] = mx;
  __syncthreads();
  if (threadIdx.x == 0) scal[0] = fmaxf(fmaxf(sm[0], sm[1]), fmaxf(sm[2], sm[3]));
}

// ---------------------------------------------------------------------------
// bias_g2: bias2[h][n][224] bf16 = tab[rpi[n][m]][h] ; m>=196 -> -inf
// ---------------------------------------------------------------------------
__launch_bounds__(256)
__global__ void bias_g2(const int* __restrict__ rpi, const float* __restrict__ tab,
                        unsigned short* __restrict__ bias2)
{
  const int tid = blockIdx.x * 256 + threadIdx.x;
  const int n = tid / MP, m = tid - n * MP;
  if (m < PLn) {
    const int idx = rpi[(size_t)n * PLn + m];
    #pragma unroll
    for (int h = 0; h < NHn; ++h)
      bias2[((size_t)h * Nn + n) * MP + m] = f2b(tab[(size_t)idx * NHn + h]);
  } else {
    #pragma unroll
    for (int h = 0; h < NHn; ++h)
      bias2[((size_t)h * Nn + n) * MP + m] = 0xFF80;   // bf16 -inf
  }
}

// ---------------------------------------------------------------------------
// attn_f: FUSED attention. Phase 1-2: MFMA pool part (per wave, 16 q-rows).
// Pool partials parked in the wave's own (dead) P-strip in LDS -- the wave
// that wrote rows [w*16,w*16+16) is exactly the wave whose threads t>>2 read
// them, so no barrier is needed. Phase 3: local 9-key part, 4 lanes per n
// (8 d each), 32-d dots completed via shfl_xor(1,2); combine + store bf16.
// Small tables live in unused v_lds rows 33..47 (their garbage MFMA reads
// only feed discarded C-columns 33..47).
// ---------------------------------------------------------------------------
__launch_bounds__(256)
__global__ void attn_f(const unsigned short* __restrict__ fused,
                       const unsigned short* __restrict__ kbf,
                       const unsigned short* __restrict__ vbf,
                       const unsigned short* __restrict__ bias2,
                       const float* __restrict__ Mq, const float* __restrict__ scal,
                       const float* __restrict__ slsp, const float* __restrict__ temp,
                       const float* __restrict__ qe, const float* __restrict__ lt,
                       const float* __restrict__ lb, const float* __restrict__ rpb,
                       unsigned short* __restrict__ outp)
{
  __shared__ __align__(16) unsigned short sh[32256];   // 63 KB
  unsigned short* k_lds = sh;              // [224][32]
  unsigned short* v_lds = sh + 7168;       // [48][224]; rows 33+ reused for tables
  unsigned short* p_lds = sh + 17920;      // 4 strips of [16][224]
  float* tabf = (float*)(v_lds + 33 * MP); // small tables: qe[32] lt[288] lb[9] rpb[9]
  float* qe_s  = tabf;
  float* lt_s  = tabf + 32;
  float* lb_s  = tabf + 320;
  float* rpb_s = tabf + 329;
  const int t = threadIdx.x;
  const int w = t >> 6, lane = t & 63;
  const int ln = lane & 15, quad = lane >> 4;
  const int tile = blockIdx.x, h = blockIdx.y, b = blockIdx.z;
  const int bh = b * NHn + h;

  {
    const uint4* gk = (const uint4*)(kbf + (size_t)bh * (MP * HDn));
    uint4* lk = (uint4*)k_lds;
    for (int i = t; i < 896; i += 256) lk[i] = gk[i];
    const uint4* gv = (const uint4*)(vbf + (size_t)bh * (33 * MP));
    uint4* lv = (uint4*)v_lds;
    for (int i = t; i < 924; i += 256) lv[i] = gv[i];
    if (t < 32) qe_s[t] = qe[h * HDn + t];
    for (int i = t; i < HDn * LLn; i += 256) lt_s[i] = lt[h * HDn * LLn + i];
    if (t < LLn) { lb_s[t] = lb[h * LLn + t]; rpb_s[t] = rpb[h * LLn + t]; }
  }
  __syncthreads();

  // ---- pool part (MFMA), wave w owns q-rows nb..nb+15 ----
  const int nb = tile * 64 + w * 16;
  const short8v afrag = *(const short8v*)(fused +
      ((size_t)(b * Nn + nb + ln)) * 1024 + h * HDn + quad * 8);
  float M4[4];
  const float sc = scal[0];
  #pragma unroll
  for (int r = 0; r < 4; ++r) M4[r] = Mq[(size_t)bh * Nn + nb + quad * 4 + r] + sc;

  unsigned short* pst = p_lds + w * (16 * MP);
  #pragma unroll
  for (int mt = 0; mt < 14; ++mt) {
    short8v bfrag = *(const short8v*)(k_lds + (mt * 16 + ln) * HDn + quad * 8);
    float4v s = __builtin_amdgcn_mfma_f32_16x16x32_bf16(afrag, bfrag,
                                                        (float4v){0.f,0.f,0.f,0.f}, 0, 0, 0);
    #pragma unroll
    for (int r = 0; r < 4; ++r) {
      const int nr = nb + quad * 4 + r;
      const float bv = b2f(bias2[((size_t)h * Nn + nr) * MP + mt * 16 + ln]);
      const float p = __expf(s[r] + bv - M4[r]);
      pst[(quad * 4 + r) * MP + mt * 16 + ln] = f2b(p);
    }
  }

  float4v accO[3];
  accO[0] = (float4v){0.f,0.f,0.f,0.f};
  accO[1] = (float4v){0.f,0.f,0.f,0.f};
  accO[2] = (float4v){0.f,0.f,0.f,0.f};
  #pragma unroll
  for (int kc = 0; kc < 7; ++kc) {
    short8v pa = *(const short8v*)(pst + ln * MP + kc * 32 + quad * 8);
    #pragma unroll
    for (int nt = 0; nt < 3; ++nt) {
      short8v vb = *(const short8v*)(v_lds + (nt * 16 + ln) * MP + kc * 32 + quad * 8);
      accO[nt] = __builtin_amdgcn_mfma_f32_16x16x32_bf16(pa, vb, accO[nt], 0, 0, 0);
    }
  }
  // park pool partials in this wave's own (dead) P strip: [16 rows][33] fp32
  float* pool_w = (float*)pst;
  #pragma unroll
  for (int r = 0; r < 4; ++r) {
    const int row = quad * 4 + r;
    pool_w[row * 33 + ln]      = accO[0][r];
    pool_w[row * 33 + 16 + ln] = accO[1][r];
    if (ln == 0) pool_w[row * 33 + 32] = accO[2][r];
  }

  // ---- local part: thread t -> n = tile*64 + (t>>2), d-slice dg = t&3 ----
  const int nl = t >> 2, dg = t & 3;
  const int n = tile * 64 + nl;
  const unsigned short* qp = fused + ((size_t)(b * Nn + n)) * 1024 + h * HDn + dg * 8;
  float qs8[8];
  u4_to8f(*(const uint4*)qp, qs8);
  const float M = Mq[(size_t)bh * Nn + n] + sc;
  const float spt = log1pf(__expf(temp[h]));
  const float inv_qs = 1.f / (spt * slsp[n]);

  float acc8[8], ext8[8];
  #pragma unroll
  for (int j = 0; j < 8; ++j) { acc8[j] = 0.f; ext8[j] = 0.f; }
  float l_run = 0.f;
  const int pi = n / Wn, pj = n % Wn;
  #pragma unroll
  for (int lc = 0; lc < LLn; ++lc) {
    const int ii = pi + lc/3 - 1, jj = pj + (lc%3) - 1;
    if (ii < 0 || ii >= Hh || jj < 0 || jj >= Wn) continue;   // uniform in 4-group
    const int nb2 = ii * Wn + jj;
    const unsigned short* kr = fused + ((size_t)(b * Nn + nb2)) * 1024 + 256 + h * HDn + dg * 8;
    float kk8[8], vv8[8];
    u4_to8f(*(const uint4*)kr, kk8);
    u4_to8f(*(const uint4*)(kr + 256), vv8);      // v = k col + 256 (same row)
    float pp = 0.f, ep = 0.f;
    #pragma unroll
    for (int j = 0; j < 8; ++j) {
      pp += qs8[j] * kk8[j];
      ep += (qs8[j] * inv_qs - qe_s[dg*8 + j]) * lt_s[(dg*8 + j) * LLn + lc];
    }
    pp += __shfl_xor(pp, 1); pp += __shfl_xor(pp, 2);
    ep += __shfl_xor(ep, 1); ep += __shfl_xor(ep, 2);
    const float e = ep + lb_s[lc];
    const float p = __expf(pp + rpb_s[lc] - M);
    l_run += p;
    #pragma unroll
    for (int j = 0; j < 8; ++j) { acc8[j] += p * vv8[j]; ext8[j] += e * vv8[j]; }
  }

  // combine with pool partials (this wave's strip; no barrier needed)
  const float* pool_r = (float*)(p_lds + w * (16 * MP)) + (nl - w * 16) * 33;
  const float l_pool = pool_r[32];
  const float invl = 1.f / (l_run + l_pool);
  uint4 u;
  {
    const float* op = pool_r + dg * 8;
    float o0 = (acc8[0]+op[0])*invl + ext8[0], o1 = (acc8[1]+op[1])*invl + ext8[1];
    float o2 = (acc8[2]+op[2])*invl + ext8[2], o3 = (acc8[3]+op[3])*invl + ext8[3];
    float o4 = (acc8[4]+op[4])*invl + ext8[4], o5 = (acc8[5]+op[5])*invl + ext8[5];
    float o6 = (acc8[6]+op[6])*invl + ext8[6], o7 = (acc8[7]+op[7])*invl + ext8[7];
    u.x = f2b(o0) | ((unsigned int)f2b(o1) << 16);
    u.y = f2b(o2) | ((unsigned int)f2b(o3) << 16);
    u.z = f2b(o4) | ((unsigned int)f2b(o5) << 16);
    u.w = f2b(o6) | ((unsigned int)f2b(o7) << 16);
  }
  *(uint4*)(outp + ((size_t)b * Nn + n) * Cn + h * HDn + dg * 8) = u;
}

// ---------------------------------------------------------------------------
extern "C" void kernel_launch(void* const* d_in, const int* in_sizes, int n_in,
                              void* d_out, int out_size, void* d_ws, size_t ws_size,
                              hipStream_t stream)
{
  const float* x    = (const float*)d_in[0];
  const int*   rpi  = (const int*)d_in[3];
  const float* rct  = (const float*)d_in[4];
  const float* sls  = (const float*)d_in[5];
  const float* q_w  = (const float*)d_in[7];
  const float* q_b  = (const float*)d_in[8];
  const float* kv_w = (const float*)d_in[9];
  const float* kv_b = (const float*)d_in[10];
  const float* sr_w = (const float*)d_in[11];
  const float* sr_b = (const float*)d_in[12];
  const float* ng   = (const float*)d_in[13];
  const float* nbta = (const float*)d_in[14];
  const float* c1w  = (const float*)d_in[15];
  const float* c1b  = (const float*)d_in[16];
  const float* c2w  = (const float*)d_in[17];
  const float* c2b  = (const float*)d_in[18];
  const float* temp = (const float*)d_in[19];
  const float* qe   = (const float*)d_in[20];
  const float* rpb  = (const float*)d_in[21];
  const float* lt   = (const float*)d_in[22];
  const float* lb   = (const float*)d_in[23];
  const float* pw   = (const float*)d_in[24];
  const float* pb   = (const float*)d_in[25];

  float* ws = (float*)d_ws;
  size_t o = 0;
  unsigned short* bf = (unsigned short*)(ws + o); o += TOTCVT / 2;
  unsigned short* fused = (unsigned short*)(ws + o); o += (size_t)Mrows * 512;  // bf16 [12544][1024]
  float* Mq    = ws + o;  o += (size_t)Bn * NHn * Nn;
  float* pln   = ws + o;  o += (size_t)Bn * PLn * Cn;
  float* kvp   = ws + o;  o += (size_t)Bn * PLn * 2 * Cn;
  unsigned short* kbf = (unsigned short*)(ws + o); o += (size_t)Bn * NHn * MP * HDn / 2;
  unsigned short* vbf = (unsigned short*)(ws + o); o += (size_t)Bn * NHn * 33 * MP / 2;
  float* tab   = ws + o;  o += (size_t)KTABn * NHn;
  float* scal  = ws + o;  o += 8;
  unsigned short* bias2 = (unsigned short*)(ws + o); o += (size_t)NHn * Nn * MP / 2;
  unsigned short* outp  = (unsigned short*)(ws + o); o += (size_t)Mrows * Cn / 2;

  const unsigned short* xbf   = bf;
  const unsigned short* qkvsw = bf + QWOFF;
  const unsigned short* pwbf  = bf + PWOFF;

  cvt5<<<TOTCVT/1024, 256, 0, stream>>>(x, q_w, kv_w, sr_w, pw, bf);
  mgemm<1><<<dim3(8, 98), 512, 0, stream>>>(xbf, qkvsw, q_b, kv_b, sr_b, fused, 1024,
                                            sls, qe, temp, Mq);
  pool_ln_k<<<Bn*PLn, 256, 0, stream>>>(fused, pln, ng, nbta);
  gemm_k<<<dim3(8, 13), 256, 0, stream>>>(pln, kv_w, kv_b, kvp, Bn*PLn, 512, 256);
  pool_pack<<<Bn*NHn, 256, 0, stream>>>(kvp, kbf, vbf);
  cpb_k<<<KTABn, 64, 0, stream>>>(rct, c1w, c1b, c2w, c2b, tab);
  redmax_k<<<1, 256, 0, stream>>>(tab, rpb, scal);
  bias_g2<<<(Nn*MP)/256, 256, 0, stream>>>(rpi, tab, bias2);
  attn_f<<<dim3(49, NHn, Bn), 256, 0, stream>>>(fused, kbf, vbf, bias2, Mq, scal,
                                                sls, temp, qe, lt, lb, rpb, outp);
  mgemm<0><<<dim3(2, 98), 512, 0, stream>>>(outp, pwbf, pb, pb, pb, (float*)d_out, 256,
                                            nullptr, nullptr, nullptr, nullptr);
}